// Round 13
// baseline (169.654 us; speedup 1.0000x reference)
//
#include <hip/hip_runtime.h>
#include <cstdint>
#include <cstddef>

// Only layer i=1 is live (reference loop re-reads x, so layer 0 is dead code).
// B=8, S=512, D=1024, H=16, DH=64. All GEMMs are M=4096, K=1024.
// All intermediates bf16; only final LN writes f32.
// NOTE: rocprof per-dispatch GEMM timings are DVFS/cold-L2 artifacts (57ms
// replay gaps) — only e2e dur_us is trusted. e2e-best GEMM = r9 structure.

typedef __attribute__((ext_vector_type(8))) short bf16x8;
typedef __attribute__((ext_vector_type(4))) short bf16x4;
typedef __attribute__((ext_vector_type(4))) float f32x4;

#define MFMA16(a, b, c) __builtin_amdgcn_mfma_f32_16x16x32_bf16((a), (b), (c), 0, 0, 0)

__device__ __forceinline__ unsigned short f2b(float f) {
  union { float f; unsigned int u; } x; x.f = f;
  unsigned int r = x.u + 0x7fffu + ((x.u >> 16) & 1u);
  return (unsigned short)(r >> 16);
}

__device__ __forceinline__ float b2f(unsigned short u) {
  union { unsigned int i; float f; } x;
  x.i = ((unsigned int)u) << 16;
  return x.f;
}

__device__ __forceinline__ void gl_lds16(const void* g, void* l) {
  __builtin_amdgcn_global_load_lds(
      (const __attribute__((address_space(1))) void*)g,
      (__attribute__((address_space(3))) void*)l, 16, 0, 0);
}

// ---------------------------------------------------------------------------
// GEMM (r9 structure verbatim — e2e-best 155.0): BM=128, BK=64, BN templated.
// 3-deep pipelined staging, COUNTED vmcnt, raw s_barrier once per K-step,
// vmcnt(0) only at tail. Pre-swizzled global source (conflict-free).
// NEW: optional split-K (KH=2): kh = (r>>3)/nnHalf picks K-half; each half
// writes a bf16 PARTIAL (out0/out1); bias folded into kh==0. Consumer LN sums.
// EPI: 1 = +bias, cols<1024 scaled 1/8; 2 = GELU; 3 = +bias(kh0 only).
// 1D grid, bijective XCD mapping: xcd=bid&7 owns an 8m x (nnHalf*KH) region.
// ---------------------------------------------------------------------------
template <int BN, int EPI>
__global__ __launch_bounds__(256) void gemm_t(
    const unsigned short* __restrict__ A, const unsigned short* __restrict__ B,
    const float* __restrict__ bias, unsigned short* __restrict__ out0,
    unsigned short* __restrict__ out1, int N, int K, int nnHalf, int KH) {
  extern __shared__ char smem[];
  char* la = smem;              // 3 x [128 rows][128 B]
  char* lb = smem + 3 * 16384;  // 3 x [BN rows][128 B]
  constexpr int NR = BN / 32;
  const int tid = threadIdx.x;
  const int l = tid & 63, w = tid >> 6;
  const int l15 = l & 15, l4 = l >> 4;
  const int xcd = blockIdx.x & 7, r = blockIdx.x >> 3;
  const int m0 = ((xcd >> 1) * 8 + (r & 7)) * 128;
  const int nk = r >> 3;
  const int nIdx = nk % nnHalf;
  const int kh = nk / nnHalf;
  const int n0 = ((xcd & 1) * nnHalf + nIdx) * BN;
  const int kOff = kh * (K / KH);
  const int wr = (w >> 1) * 64, wc = (w & 1) * (BN / 2);
  const int NT = (K / KH) >> 6;  // K-steps of 64

#define STAGE(buf, t)                                                         \
  {                                                                           \
    const int k0_ = kOff + (t) * 64;                                          \
    _Pragma("unroll") for (int i = 0; i < 4; ++i) {                           \
      const int c = i * 256 + tid;                                            \
      const int row = c >> 3;                                                 \
      const int gch = (c & 7) ^ (row & 7);                                    \
      gl_lds16(A + (size_t)(m0 + row) * K + k0_ + gch * 8,                    \
               la + (buf) * 16384 + (i * 256 + w * 64) * 16);                 \
    }                                                                         \
    _Pragma("unroll") for (int i = 0; i < BN / 32; ++i) {                     \
      const int c = i * 256 + tid;                                            \
      const int row = c >> 3;                                                 \
      const int gch = (c & 7) ^ (row & 7);                                    \
      gl_lds16(B + (size_t)(n0 + row) * K + k0_ + gch * 8,                    \
               lb + (buf) * (BN * 128) + (i * 256 + w * 64) * 16);            \
    }                                                                         \
  }
#define WAIT_L()                                                   \
  {                                                                \
    if constexpr (BN == 128) {                                     \
      asm volatile("s_waitcnt vmcnt(8)" ::: "memory");             \
    } else {                                                       \
      asm volatile("s_waitcnt vmcnt(6)" ::: "memory");             \
    }                                                              \
  }

  f32x4 acc[4][NR] = {};
  const int sw = l15 & 7;

  STAGE(0, 0);
  STAGE(1, 1);
  WAIT_L();  // tile 0 landed (tile 1 still in flight)
  __builtin_amdgcn_sched_barrier(0);
  __builtin_amdgcn_s_barrier();
  __builtin_amdgcn_sched_barrier(0);

  for (int t = 0; t < NT; ++t) {
    if (t + 2 < NT) {
      STAGE((t + 2) % 3, t + 2);
    }
    __builtin_amdgcn_sched_barrier(0);
    const char* abuf = la + (t % 3) * 16384;
    const char* bbuf = lb + (t % 3) * (BN * 128);
#pragma unroll
    for (int kk = 0; kk < 2; ++kk) {
      const unsigned int ch = (unsigned int)(((kk * 4 + l4) ^ sw) << 4);
      bf16x8 af[4], bfr[NR];
#pragma unroll
      for (int m = 0; m < 4; ++m)
        af[m] = *(const bf16x8*)(abuf + (wr + m * 16 + l15) * 128 + ch);
#pragma unroll
      for (int n = 0; n < NR; ++n)
        bfr[n] = *(const bf16x8*)(bbuf + (wc + n * 16 + l15) * 128 + ch);
#pragma unroll
      for (int m = 0; m < 4; ++m) {
#pragma unroll
        for (int n = 0; n < NR; ++n) {
          acc[m][n] = MFMA16(af[m], bfr[n], acc[m][n]);
        }
      }
    }
    if (t < NT - 1) {
      if (t + 2 < NT) {
        WAIT_L();  // tile t+1 landed; tile t+2 still in flight
      } else {
        asm volatile("s_waitcnt vmcnt(0)" ::: "memory");  // tail drain
      }
      __builtin_amdgcn_sched_barrier(0);
      __builtin_amdgcn_s_barrier();
      __builtin_amdgcn_sched_barrier(0);
    }
  }
#undef STAGE
#undef WAIT_L

  unsigned short* outp = kh ? out1 : out0;
#pragma unroll
  for (int m = 0; m < 4; ++m) {
#pragma unroll
    for (int n = 0; n < NR; ++n) {
      const int col = n0 + wc + n * 16 + l15;
      const float bb = (kh == 0) ? bias[col] : 0.f;
#pragma unroll
      for (int e = 0; e < 4; ++e) {
        const int row = m0 + wr + m * 16 + l4 * 4 + e;
        float v = acc[m][n][e] + bb;
        if (EPI == 1) {
          if (col < 1024) v *= 0.125f;  // fold 1/sqrt(DH) into Q
        } else if (EPI == 2) {
          v = 0.5f * v * (1.f + erff(v * 0.70710678118654752f));
        }
        outp[(size_t)row * N + col] = f2b(v);
      }
    }
  }
}

// ---------------------------------------------------------------------------
// Attention v5 (unchanged, passing): flash-tiled, double-buffered LDS staging
// of K AND V, XCD-local b=bid&7 mapping, swizzled K/V^T, T14 split.
// ---------------------------------------------------------------------------
__global__ __launch_bounds__(256, 2) void attn_kernel(
    const unsigned short* __restrict__ qkv, const int* __restrict__ mask,
    unsigned short* __restrict__ ctx) {
  extern __shared__ char smem[];
  float* maskadd = (float*)(smem + 65536);  // [512]
  const int bid = blockIdx.x;
  const int b = bid & 7, h = (bid >> 3) & 15, qt = bid >> 7;
  const int tid = threadIdx.x, l = tid & 63, w = tid >> 6;
  const int l15 = l & 15, l4 = l >> 4;
  const size_t RB = (size_t)b * 512 * 3072;

  for (int s = tid; s < 512; s += 256)
    maskadd[s] = mask[b * 512 + s] ? 0.f : -1e18f;

  const unsigned short* Kbase = qkv + RB + 1024 + h * 64;
  const unsigned short* Vbase = qkv + RB + 2048 + h * 64;

  const int kr0 = tid >> 2, kc0 = tid & 3;
  const unsigned int swzk = (unsigned int)((kr0 & 7) << 4);
  const unsigned int ka0 = ((unsigned int)(kr0 * 128 + kc0 * 16)) ^ swzk;
  const unsigned int ka1 = ((unsigned int)(kr0 * 128 + kc0 * 16 + 64)) ^ swzk;
  const int vs0 = 2 * l, vd0 = w * 16;

  bf16x8 k00, k01, k10, k11, vreg[4];
  k00 = *(const bf16x8*)(Kbase + (size_t)kr0 * 3072 + kc0 * 8);
  k01 = *(const bf16x8*)(Kbase + (size_t)kr0 * 3072 + kc0 * 8 + 32);
  k10 = *(const bf16x8*)(Kbase + (size_t)(kr0 + 64) * 3072 + kc0 * 8);
  k11 = *(const bf16x8*)(Kbase + (size_t)(kr0 + 64) * 3072 + kc0 * 8 + 32);
  vreg[0] = *(const bf16x8*)(Vbase + (size_t)vs0 * 3072 + vd0);
  vreg[1] = *(const bf16x8*)(Vbase + (size_t)vs0 * 3072 + vd0 + 8);
  vreg[2] = *(const bf16x8*)(Vbase + (size_t)(vs0 + 1) * 3072 + vd0);
  vreg[3] = *(const bf16x8*)(Vbase + (size_t)(vs0 + 1) * 3072 + vd0 + 8);

  const int q0 = qt * 64 + w * 16;
  const unsigned short* qb =
      qkv + RB + (size_t)(q0 + l15) * 3072 + h * 64 + l4 * 8;
  const bf16x8 qf0 = *(const bf16x8*)(qb);
  const bf16x8 qf1 = *(const bf16x8*)(qb + 32);

#define KWRITE(dst)                        \
  {                                        \
    *(bf16x8*)((dst) + ka0) = k00;         \
    *(bf16x8*)((dst) + ka1) = k01;         \
    *(bf16x8*)((dst) + ka0 + 8192) = k10;  \
    *(bf16x8*)((dst) + ka1 + 8192) = k11;  \
  }
#define VWRITE(dst)                                                          \
  {                                                                          \
    _Pragma("unroll") for (int j = 0; j < 16; ++j) {                         \
      const unsigned short lo_ =                                             \
          (unsigned short)((j < 8) ? vreg[0][j] : vreg[1][j - 8]);           \
      const unsigned short hi_ =                                             \
          (unsigned short)((j < 8) ? vreg[2][j] : vreg[3][j - 8]);           \
      *(unsigned int*)((dst) +                                               \
                       (((vd0 + j) * 256 + vs0 * 2) ^ ((j & 7) << 4))) =     \
          (unsigned int)lo_ | ((unsigned int)hi_ << 16);                     \
    }                                                                        \
  }

  KWRITE(smem);
  VWRITE(smem + 32768);
  __syncthreads();

  const int hi4 = l4 >> 1, gl = l4 & 1, g2 = l4 & 2;
  f32x4 acc[4] = {};
  float run_m = -1e30f, run_s = 0.f;

#pragma unroll
  for (int t = 0; t < 4; ++t) {
    char* kcur = smem + (t & 1) * 16384;
    char* vcur = smem + 32768 + (t & 1) * 16384;
    if (t < 3) {
      const int sn = (t + 1) * 128;
      k00 = *(const bf16x8*)(Kbase + (size_t)(sn + kr0) * 3072 + kc0 * 8);
      k01 = *(const bf16x8*)(Kbase + (size_t)(sn + kr0) * 3072 + kc0 * 8 + 32);
      k10 = *(const bf16x8*)(Kbase + (size_t)(sn + kr0 + 64) * 3072 + kc0 * 8);
      k11 = *(const bf16x8*)(Kbase + (size_t)(sn + kr0 + 64) * 3072 + kc0 * 8 + 32);
      vreg[0] = *(const bf16x8*)(Vbase + (size_t)(sn + vs0) * 3072 + vd0);
      vreg[1] = *(const bf16x8*)(Vbase + (size_t)(sn + vs0) * 3072 + vd0 + 8);
      vreg[2] = *(const bf16x8*)(Vbase + (size_t)(sn + vs0 + 1) * 3072 + vd0);
      vreg[3] = *(const bf16x8*)(Vbase + (size_t)(sn + vs0 + 1) * 3072 + vd0 + 8);
      __builtin_amdgcn_sched_barrier(0);
    }
    f32x4 sc[8];
    __builtin_amdgcn_s_setprio(1);
#pragma unroll
    for (int kk = 0; kk < 8; ++kk) {
      const unsigned int lin = (unsigned int)((kk * 16 + l15) * 128 + l4 * 16);
      const unsigned int swz = (unsigned int)((l15 & 7) << 4);
      const bf16x8 af0 = *(const bf16x8*)(kcur + (lin ^ swz));
      const bf16x8 af1 = *(const bf16x8*)(kcur + ((lin + 64) ^ swz));
      f32x4 c = {0.f, 0.f, 0.f, 0.f};
      c = MFMA16(af0, qf0, c);
      c = MFMA16(af1, qf1, c);
      sc[kk] = c;
    }
    __builtin_amdgcn_s_setprio(0);
    float tmx = -1e30f;
#pragma unroll
    for (int kk = 0; kk < 8; ++kk) {
#pragma unroll
      for (int e = 0; e < 4; ++e) {
        const float v = sc[kk][e] + maskadd[t * 128 + kk * 16 + l4 * 4 + e];
        sc[kk][e] = v;
        tmx = fmaxf(tmx, v);
      }
    }
    tmx = fmaxf(tmx, __shfl_xor(tmx, 16));
    tmx = fmaxf(tmx, __shfl_xor(tmx, 32));
    const float nm = (t == 0) ? tmx : fmaxf(run_m, tmx);
    float tsum = 0.f;
    unsigned int pk[8][2];
#pragma unroll
    for (int kk = 0; kk < 8; ++kk) {
      const float p0 = __expf(sc[kk][0] - nm);
      const float p1 = __expf(sc[kk][1] - nm);
      const float p2 = __expf(sc[kk][2] - nm);
      const float p3 = __expf(sc[kk][3] - nm);
      tsum += (p0 + p1) + (p2 + p3);
      asm("v_cvt_pk_bf16_f32 %0, %1, %2" : "=v"(pk[kk][0]) : "v"(p0), "v"(p1));
      asm("v_cvt_pk_bf16_f32 %0, %1, %2" : "=v"(pk[kk][1]) : "v"(p2), "v"(p3));
    }
    tsum += __shfl_xor(tsum, 16);
    tsum += __shfl_xor(tsum, 32);
    if (t == 0) {
      run_s = tsum;
    } else {
      const float scale = __expf(run_m - nm);
      run_s = run_s * scale + tsum;
      float s4[4];
#pragma unroll
      for (int e = 0; e < 4; ++e) s4[e] = __shfl(scale, l4 * 4 + e);
#pragma unroll
      for (int nt = 0; nt < 4; ++nt) {
#pragma unroll
        for (int e = 0; e < 4; ++e) acc[nt][e] *= s4[e];
      }
    }
    run_m = nm;
#pragma unroll
    for (int k2 = 0; k2 < 4; ++k2) {
      const unsigned int own0 = hi4 ? pk[2 * k2 + 1][0] : pk[2 * k2][0];
      const unsigned int own1 = hi4 ? pk[2 * k2 + 1][1] : pk[2 * k2][1];
      const unsigned int oth0 = hi4 ? pk[2 * k2][0] : pk[2 * k2 + 1][0];
      const unsigned int oth1 = hi4 ? pk[2 * k2][1] : pk[2 * k2 + 1][1];
      const unsigned int s16_0 = (unsigned int)__shfl_xor((int)own0, 16);
      const unsigned int s16_1 = (unsigned int)__shfl_xor((int)own1, 16);
      const unsigned int s32_0 = (unsigned int)__shfl_xor((int)oth0, 32);
      const unsigned int s32_1 = (unsigned int)__shfl_xor((int)oth1, 32);
      const unsigned int s48_0 = (unsigned int)__shfl_xor((int)oth0, 48);
      const unsigned int s48_1 = (unsigned int)__shfl_xor((int)oth1, 48);
      union { unsigned int u[4]; bf16x8 v; } pa;
      pa.u[0] = g2 ? (gl ? s16_0 : s32_0) : (gl ? s48_0 : own0);
      pa.u[1] = g2 ? (gl ? s16_1 : s32_1) : (gl ? s48_1 : own1);
      pa.u[2] = g2 ? (gl ? own0 : s48_0) : (gl ? s32_0 : s16_0);
      pa.u[3] = g2 ? (gl ? own1 : s48_1) : (gl ? s32_1 : s16_1);
      __builtin_amdgcn_s_setprio(1);
#pragma unroll
      for (int nt = 0; nt < 4; ++nt) {
        const int d = nt * 16 + l15;
        const unsigned int vb =
            (unsigned int)((d * 256 + k2 * 64 + l4 * 16) ^ ((l15 & 7) << 4));
        const bf16x8 vbf = *(const bf16x8*)(vcur + vb);
        acc[nt] = MFMA16(pa.v, vbf, acc[nt]);
      }
      __builtin_amdgcn_s_setprio(0);
    }
    if (t < 3) {
      char* knxt = smem + ((t + 1) & 1) * 16384;
      char* vnxt = smem + 32768 + ((t + 1) & 1) * 16384;
      KWRITE(knxt);
      VWRITE(vnxt);
      __syncthreads();
    }
  }
#undef KWRITE
#undef VWRITE

  const float inv = 1.f / run_s;
  float invq[4];
#pragma unroll
  for (int e = 0; e < 4; ++e) invq[e] = __shfl(inv, l4 * 4 + e);
#pragma unroll
  for (int nt = 0; nt < 4; ++nt) {
#pragma unroll
    for (int e = 0; e < 4; ++e) {
      const size_t row = (size_t)b * 512 + q0 + l4 * 4 + e;
      ctx[row * 1024 + h * 64 + nt * 16 + l15] = f2b(acc[nt][e] * invq[e]);
    }
  }
}

// ---------------------------------------------------------------------------
// LN over two bf16 partials + bf16 residual (split-K reduction fused in).
// MODE 3: out bf16.  MODE 4: out f32.
// ---------------------------------------------------------------------------
template <int MODE>
__global__ __launch_bounds__(256) void ln_k(
    const unsigned short* __restrict__ A0, const unsigned short* __restrict__ A1,
    const unsigned short* __restrict__ Rp, const float* __restrict__ g,
    const float* __restrict__ bta, void* __restrict__ outp) {
  __shared__ float red[8];
  const int row = blockIdx.x, tid = threadIdx.x;
  const size_t base = (size_t)row * 1024 + tid * 4;
  float a4[4];
  {
    const bf16x4 a = *(const bf16x4*)(A0 + base);
    const bf16x4 a2 = *(const bf16x4*)(A1 + base);
    const bf16x4 rr = *(const bf16x4*)(Rp + base);
#pragma unroll
    for (int j = 0; j < 4; ++j)
      a4[j] = b2f((unsigned short)a[j]) + b2f((unsigned short)a2[j]) +
              b2f((unsigned short)rr[j]);
  }
  float s = a4[0] + a4[1] + a4[2] + a4[3];
  float q = a4[0] * a4[0] + a4[1] * a4[1] + a4[2] * a4[2] + a4[3] * a4[3];
#pragma unroll
  for (int o = 32; o; o >>= 1) {
    s += __shfl_xor(s, o);
    q += __shfl_xor(q, o);
  }
  if ((tid & 63) == 0) {
    red[(tid >> 6) * 2] = s;
    red[(tid >> 6) * 2 + 1] = q;
  }
  __syncthreads();
  const float S = red[0] + red[2] + red[4] + red[6];
  const float Qs = red[1] + red[3] + red[5] + red[7];
  const float mean = S * (1.f / 1024.f);
  float var = (Qs - 1024.f * mean * mean) * (1.f / 1023.f);
  var = fmaxf(var, 0.f);
  const float inv = 1.f / (sqrtf(var) + 1e-6f);
  if (MODE == 4) {
    float4 o4;
    o4.x = g[tid * 4 + 0] * (a4[0] - mean) * inv + bta[tid * 4 + 0];
    o4.y = g[tid * 4 + 1] * (a4[1] - mean) * inv + bta[tid * 4 + 1];
    o4.z = g[tid * 4 + 2] * (a4[2] - mean) * inv + bta[tid * 4 + 2];
    o4.w = g[tid * 4 + 3] * (a4[3] - mean) * inv + bta[tid * 4 + 3];
    *(float4*)((float*)outp + base) = o4;
  } else {
    bf16x4 pb;
#pragma unroll
    for (int j = 0; j < 4; ++j) {
      const int col = tid * 4 + j;
      pb[j] = (short)f2b(g[col] * (a4[j] - mean) * inv + bta[col]);
    }
    *(bf16x4*)((unsigned short*)outp + base) = pb;
  }
}

// ---------------------------------------------------------------------------
// Fused: input LN (+PE) for blocks < 4096; weight f32->bf16 convert + bias
// pack for the rest. One dispatch instead of two.
// ---------------------------------------------------------------------------
__global__ __launch_bounds__(256) void prep_ln(
    const float* __restrict__ features, const float* __restrict__ g,
    const float* __restrict__ bta, unsigned short* __restrict__ xb,
    const float* __restrict__ Wq, const float* __restrict__ Wk,
    const float* __restrict__ Wv, const float* __restrict__ Wo,
    const float* __restrict__ W1, const float* __restrict__ W2,
    const float* __restrict__ bq, const float* __restrict__ bk,
    const float* __restrict__ bv, unsigned short* __restrict__ wqkv,
    unsigned short* __restrict__ wo, unsigned short* __restrict__ w1,
    unsigned short* __restrict__ w2, float* __restrict__ bqkv) {
  if (blockIdx.x < 4096) {
    __shared__ float red[8];
    const int row = blockIdx.x, tid = threadIdx.x;
    const size_t base = (size_t)row * 1024 + tid * 4;
    const float4 a = *(const float4*)(features + base);
    float a4[4] = {a.x, a.y, a.z, a.w};
    float s = a4[0] + a4[1] + a4[2] + a4[3];
    float q = a4[0] * a4[0] + a4[1] * a4[1] + a4[2] * a4[2] + a4[3] * a4[3];
#pragma unroll
    for (int o = 32; o; o >>= 1) {
      s += __shfl_xor(s, o);
      q += __shfl_xor(q, o);
    }
    if ((tid & 63) == 0) {
      red[(tid >> 6) * 2] = s;
      red[(tid >> 6) * 2 + 1] = q;
    }
    __syncthreads();
    const float S = red[0] + red[2] + red[4] + red[6];
    const float Qs = red[1] + red[3] + red[5] + red[7];
    const float mean = S * (1.f / 1024.f);
    float var = (Qs - 1024.f * mean * mean) * (1.f / 1023.f);
    var = fmaxf(var, 0.f);
    const float inv = 1.f / (sqrtf(var) + 1e-6f);
    bf16x4 pb;
#pragma unroll
    for (int j = 0; j < 4; ++j) {
      const int col = tid * 4 + j;
      float y = g[col] * (a4[j] - mean) * inv + bta[col];
      const float ang =
          (float)(row & 511) * exp2f((float)col * -0.025952563241307518f);
      y += (col & 1) ? cosf(ang) : sinf(ang);
      pb[j] = (short)f2b(y);
    }
    *(bf16x4*)(xb + base) = pb;
  } else {
    const int gid = (blockIdx.x - 4096) * 256 + threadIdx.x;
    if (gid < 1572864) {
      const int chunk = gid >> 18;
      const int off = (gid & 262143) * 4;
      const float* s;
      unsigned short* d;
      switch (chunk) {
        case 0: s = Wq; d = wqkv; break;
        case 1: s = Wk; d = wqkv + 1048576; break;
        case 2: s = Wv; d = wqkv + 2097152; break;
        case 3: s = Wo; d = wo; break;
        case 4: s = W1; d = w1; break;
        default: s = W2; d = w2; break;
      }
      const float4 v = *(const float4*)(s + off);
      bf16x4 o;
      o[0] = (short)f2b(v.x); o[1] = (short)f2b(v.y);
      o[2] = (short)f2b(v.z); o[3] = (short)f2b(v.w);
      *(bf16x4*)(d + off) = o;
    } else {
      const int idx = (gid - 1572864) * 4;
      if (idx < 3072) {
        const float* bs = idx < 1024 ? bq : (idx < 2048 ? bk - 1024 : bv - 2048);
        *(float4*)(bqkv + idx) = *(const float4*)(bs + idx);
      }
    }
  }
}

extern "C" void kernel_launch(void* const* d_in, const int* in_sizes, int n_in,
                              void* d_out, int out_size, void* d_ws, size_t ws_size,
                              hipStream_t stream) {
  (void)in_sizes; (void)n_in; (void)out_size; (void)ws_size;
  const float* features = (const float*)d_in[0];
  const int* mask = (const int*)d_in[1];
  const float* ln_in_g = (const float*)d_in[2];
  const float* ln_in_b = (const float*)d_in[3];
  const size_t DD = 1024 * 1024;
  // layer index 1 (the only live layer)
  const float* Wq = (const float*)d_in[4] + DD;
  const float* bq = (const float*)d_in[5] + 1024;
  const float* Wk = (const float*)d_in[6] + DD;
  const float* bk = (const float*)d_in[7] + 1024;
  const float* Wv = (const float*)d_in[8] + DD;
  const float* bv = (const float*)d_in[9] + 1024;
  const float* Wo = (const float*)d_in[10] + DD;
  const float* bo = (const float*)d_in[11] + 1024;
  const float* l1g = (const float*)d_in[12] + 1024;
  const float* l1b = (const float*)d_in[13] + 1024;
  const float* W1 = (const float*)d_in[14] + DD;
  const float* b1 = (const float*)d_in[15] + 1024;
  const float* W2 = (const float*)d_in[16] + DD;
  const float* b2 = (const float*)d_in[17] + 1024;
  const float* l2g = (const float*)d_in[18] + 1024;
  const float* l2b = (const float*)d_in[19] + 1024;

  char* base = (char*)d_ws;
  unsigned short* qkv = (unsigned short*)(base);              // 24 MB [4096][3072]
  unsigned short* xb = (unsigned short*)(base + 25165824);    // 8 MB: x bf16, then h
  unsigned short* ctxb = (unsigned short*)(base + 33554432);  // 8 MB: ctx, then s
  unsigned short* p0 = (unsigned short*)(base + 41943040);    // 8 MB partial 0
  unsigned short* p1 = (unsigned short*)(base + 50331648);    // 8 MB partial 1
  unsigned short* wqkv = (unsigned short*)(base + 58720256);  // 6 MB [3072][1024]
  unsigned short* wo = (unsigned short*)(base + 65011712);    // 2 MB
  unsigned short* w1 = (unsigned short*)(base + 67108864);    // 2 MB
  unsigned short* w2 = (unsigned short*)(base + 69206016);    // 2 MB
  float* bqkv = (float*)(base + 71303168);                    // 12 KB

  hipFuncSetAttribute((const void*)gemm_t<128, 1>,
                      hipFuncAttributeMaxDynamicSharedMemorySize, 98304);
  hipFuncSetAttribute((const void*)gemm_t<64, 2>,
                      hipFuncAttributeMaxDynamicSharedMemorySize, 73728);
  hipFuncSetAttribute((const void*)gemm_t<64, 3>,
                      hipFuncAttributeMaxDynamicSharedMemorySize, 73728);
  hipFuncSetAttribute((const void*)attn_kernel,
                      hipFuncAttributeMaxDynamicSharedMemorySize, 67584);

  // fused: x = LN(features)+PE -> bf16  AND  weight converts + bias pack
  prep_ln<<<4096 + 6147, 256, 0, stream>>>(
      features, ln_in_g, ln_in_b, xb, Wq, Wk, Wv, Wo, W1, W2, bq, bk, bv,
      wqkv, wo, w1, w2, bqkv);
  // fused QKV projection (Q pre-scaled by 1/8): 32m x 24n = 768 blocks
  gemm_t<128, 1><<<768, 256, 98304, stream>>>(xb, wqkv, bqkv, qkv, qkv, 3072,
                                              1024, 12, 1);
  // attention
  attn_kernel<<<1024, 256, 67584, stream>>>(qkv, mask, ctxb);
  // attn_out partials: ctx @ Wo^T (+bo in kh0), split-K=2: 32m x 16n x 2k
  gemm_t<64, 3><<<1024, 256, 73728, stream>>>(ctxb, wo, bo, p0, p1, 1024, 1024,
                                              8, 2);
  // s = LN(p0 + p1 + x) -> bf16
  ln_k<3><<<4096, 256, 0, stream>>>(p0, p1, xb, l1g, l1b, ctxb);
  // h = gelu(s @ W1^T + b1) -> bf16 (unsplit; GELU needs full sum)
  gemm_t<64, 2><<<512, 256, 73728, stream>>>(ctxb, w1, b1, xb, xb, 1024, 1024,
                                             8, 1);
  // f partials: h @ W2^T (+b2 in kh0), split-K=2
  gemm_t<64, 3><<<1024, 256, 73728, stream>>>(xb, w2, b2, p0, p1, 1024, 1024,
                                              8, 2);
  // out = LN(p0 + p1 + s) -> f32
  ln_k<4><<<4096, 256, 0, stream>>>(p0, p1, ctxb, l2g, l2b, (float*)d_out);
}

// Round 14
// 164.299 us; speedup vs baseline: 1.0326x; 1.0326x over previous
//
#include <hip/hip_runtime.h>
#include <cstdint>
#include <cstddef>

// Only layer i=1 is live (reference loop re-reads x, so layer 0 is dead code).
// B=8, S=512, D=1024, H=16, DH=64. All GEMMs are M=4096, K=1024.
// All intermediates bf16; only final LN writes f32.
// LDS granule insight: dynamic/static requests round up past 64KB kill
// 2-blocks/CU residency -> all worker kernels sized to <=64KB LDS.

typedef __attribute__((ext_vector_type(8))) short bf16x8;
typedef __attribute__((ext_vector_type(4))) short bf16x4;
typedef __attribute__((ext_vector_type(4))) float f32x4;

#define MFMA16(a, b, c) __builtin_amdgcn_mfma_f32_16x16x32_bf16((a), (b), (c), 0, 0, 0)

__device__ __forceinline__ unsigned short f2b(float f) {
  union { float f; unsigned int u; } x; x.f = f;
  unsigned int r = x.u + 0x7fffu + ((x.u >> 16) & 1u);
  return (unsigned short)(r >> 16);
}

__device__ __forceinline__ float b2f(unsigned short u) {
  union { unsigned int i; float f; } x;
  x.i = ((unsigned int)u) << 16;
  return x.f;
}

__device__ __forceinline__ void gl_lds16(const void* g, void* l) {
  __builtin_amdgcn_global_load_lds(
      (const __attribute__((address_space(1))) void*)g,
      (__attribute__((address_space(3))) void*)l, 16, 0, 0);
}

// ---------------------------------------------------------------------------
// QKV GEMM (r9 verbatim, e2e-best): BM=128, BN=128, BK=64, 3-deep A+B in
// dynamic 96KB LDS, counted vmcnt(8), one s_barrier/K-step, pre-swizzled
// global source (conflict-free). EPI: +bias, cols<1024 scaled 1/8 -> bf16.
// ---------------------------------------------------------------------------
__global__ __launch_bounds__(256) void gemm_qkv(
    const unsigned short* __restrict__ A, const unsigned short* __restrict__ B,
    const float* __restrict__ bias, unsigned short* __restrict__ outB, int N,
    int K, int nnHalf) {
  extern __shared__ char smem[];
  char* la = smem;              // 3 x [128][128B]
  char* lb = smem + 3 * 16384;  // 3 x [128][128B]
  const int tid = threadIdx.x;
  const int l = tid & 63, w = tid >> 6;
  const int l15 = l & 15, l4 = l >> 4;
  const int xcd = blockIdx.x & 7, r = blockIdx.x >> 3;
  const int m0 = ((xcd >> 1) * 8 + (r & 7)) * 128;
  const int n0 = ((xcd & 1) * nnHalf + (r >> 3)) * 128;
  const int wr = (w >> 1) * 64, wc = (w & 1) * 64;
  const int NT = K >> 6;

#define STAGE(buf, t)                                                         \
  {                                                                           \
    const int k0_ = (t) * 64;                                                 \
    _Pragma("unroll") for (int i = 0; i < 4; ++i) {                           \
      const int c = i * 256 + tid;                                            \
      const int row = c >> 3;                                                 \
      const int gch = (c & 7) ^ (row & 7);                                    \
      gl_lds16(A + (size_t)(m0 + row) * K + k0_ + gch * 8,                    \
               la + (buf) * 16384 + (i * 256 + w * 64) * 16);                 \
    }                                                                         \
    _Pragma("unroll") for (int i = 0; i < 4; ++i) {                           \
      const int c = i * 256 + tid;                                            \
      const int row = c >> 3;                                                 \
      const int gch = (c & 7) ^ (row & 7);                                    \
      gl_lds16(B + (size_t)(n0 + row) * K + k0_ + gch * 8,                    \
               lb + (buf) * 16384 + (i * 256 + w * 64) * 16);                 \
    }                                                                         \
  }

  f32x4 acc[4][4] = {};
  const int sw = l15 & 7;

  STAGE(0, 0);
  STAGE(1, 1);
  asm volatile("s_waitcnt vmcnt(8)" ::: "memory");
  __builtin_amdgcn_sched_barrier(0);
  __builtin_amdgcn_s_barrier();
  __builtin_amdgcn_sched_barrier(0);

  for (int t = 0; t < NT; ++t) {
    if (t + 2 < NT) {
      STAGE((t + 2) % 3, t + 2);
    }
    __builtin_amdgcn_sched_barrier(0);
    const char* abuf = la + (t % 3) * 16384;
    const char* bbuf = lb + (t % 3) * 16384;
#pragma unroll
    for (int kk = 0; kk < 2; ++kk) {
      const unsigned int ch = (unsigned int)(((kk * 4 + l4) ^ sw) << 4);
      bf16x8 af[4], bfr[4];
#pragma unroll
      for (int m = 0; m < 4; ++m)
        af[m] = *(const bf16x8*)(abuf + (wr + m * 16 + l15) * 128 + ch);
#pragma unroll
      for (int n = 0; n < 4; ++n)
        bfr[n] = *(const bf16x8*)(bbuf + (wc + n * 16 + l15) * 128 + ch);
#pragma unroll
      for (int m = 0; m < 4; ++m) {
#pragma unroll
        for (int n = 0; n < 4; ++n) {
          acc[m][n] = MFMA16(af[m], bfr[n], acc[m][n]);
        }
      }
    }
    if (t < NT - 1) {
      if (t + 2 < NT) {
        asm volatile("s_waitcnt vmcnt(8)" ::: "memory");
      } else {
        asm volatile("s_waitcnt vmcnt(0)" ::: "memory");
      }
      __builtin_amdgcn_sched_barrier(0);
      __builtin_amdgcn_s_barrier();
      __builtin_amdgcn_sched_barrier(0);
    }
  }
#undef STAGE

#pragma unroll
  for (int m = 0; m < 4; ++m) {
#pragma unroll
    for (int n = 0; n < 4; ++n) {
      const int col = n0 + wc + n * 16 + l15;
      const float bb = bias[col];
#pragma unroll
      for (int e = 0; e < 4; ++e) {
        const int row = m0 + wr + m * 16 + l4 * 4 + e;
        float v = acc[m][n][e] + bb;
        if (col < 1024) v *= 0.125f;  // fold 1/sqrt(DH) into Q
        outB[(size_t)row * N + col] = f2b(v);
      }
    }
  }
}

// ---------------------------------------------------------------------------
// Small GEMM (r11 structure verbatim, refcheck-passed): BM=128, BN=64, BK=64,
// K=1024 (NT=16). LDS EXACTLY 64KB static -> 2 blocks/CU: A 3-deep (48KB) +
// B 2-deep (16KB), both coalesced pre-swizzled global_load_lds. Counted
// vmcnt(4) per step (B(t+1)+A(t+2) issued; drains A(t+1)+B(t+1)); vmcnt(0)
// only at tail; one s_barrier/step.
// EPI: 2 = GELU -> bf16; 3 = +bias -> bf16.
// ---------------------------------------------------------------------------
template <int EPI>
__global__ __launch_bounds__(256) void gemm_s(
    const unsigned short* __restrict__ A, const unsigned short* __restrict__ B,
    const float* __restrict__ bias, unsigned short* __restrict__ outB, int N,
    int nnHalf) {
  __shared__ char la[3 * 128 * 128];  // 48KB
  __shared__ char lb[2 * 64 * 128];   // 16KB
  constexpr int K = 1024;
  constexpr int NT = 16;
  const int tid = threadIdx.x;
  const int l = tid & 63, w = tid >> 6;
  const int l15 = l & 15, l4 = l >> 4;
  const int xcd = blockIdx.x & 7, r = blockIdx.x >> 3;
  const int m0 = ((xcd >> 1) * 8 + (r & 7)) * 128;
  const int n0 = ((xcd & 1) * nnHalf + (r >> 3)) * 64;
  const int wr = (w >> 1) * 64, wc = (w & 1) * 32;
  const int sw = l15 & 7;

#define STAGE_A(buf, t)                                                       \
  {                                                                           \
    const int k0_ = (t) * 64;                                                 \
    _Pragma("unroll") for (int i = 0; i < 4; ++i) {                           \
      const int c = i * 256 + tid;                                            \
      const int row = c >> 3;                                                 \
      const int gch = (c & 7) ^ (row & 7);                                    \
      gl_lds16(A + (size_t)(m0 + row) * K + k0_ + gch * 8,                    \
               la + (buf) * 16384 + (i * 256 + w * 64) * 16);                 \
    }                                                                         \
  }
#define STAGE_B(buf, t)                                                       \
  {                                                                           \
    const int k0_ = (t) * 64;                                                 \
    _Pragma("unroll") for (int i = 0; i < 2; ++i) {                           \
      const int c = i * 256 + tid;                                            \
      const int row = c >> 3;                                                 \
      const int gch = (c & 7) ^ (row & 7);                                    \
      gl_lds16(B + (size_t)(n0 + row) * K + k0_ + gch * 8,                    \
               lb + (buf) * 8192 + (i * 256 + w * 64) * 16);                  \
    }                                                                         \
  }

  f32x4 acc[4][2] = {};

  STAGE_A(0, 0);
  STAGE_B(0, 0);
  STAGE_A(1, 1);
  // outstanding A0(4)+B0(2)+A1(4)=10 -> leave A1(4): A0,B0 landed
  asm volatile("s_waitcnt vmcnt(4)" ::: "memory");
  __builtin_amdgcn_sched_barrier(0);
  __builtin_amdgcn_s_barrier();
  __builtin_amdgcn_sched_barrier(0);

#pragma unroll
  for (int t = 0; t < NT; ++t) {
    if (t + 1 < NT) {
      STAGE_B((t + 1) & 1, t + 1);  // issued BEFORE A(t+2): retire order
    }
    if (t + 2 < NT) {
      STAGE_A((t + 2) % 3, t + 2);
    }
    __builtin_amdgcn_sched_barrier(0);
    const char* abuf = la + (t % 3) * 16384;
    const char* bbuf = lb + (t & 1) * 8192;
#pragma unroll
    for (int kk = 0; kk < 2; ++kk) {
      const unsigned int ch = (unsigned int)(((kk * 4 + l4) ^ sw) << 4);
      bf16x8 af[4], bfr[2];
#pragma unroll
      for (int m = 0; m < 4; ++m)
        af[m] = *(const bf16x8*)(abuf + (wr + m * 16 + l15) * 128 + ch);
#pragma unroll
      for (int n = 0; n < 2; ++n)
        bfr[n] = *(const bf16x8*)(bbuf + (wc + n * 16 + l15) * 128 + ch);
#pragma unroll
      for (int m = 0; m < 4; ++m) {
#pragma unroll
        for (int n = 0; n < 2; ++n) {
          acc[m][n] = MFMA16(af[m], bfr[n], acc[m][n]);
        }
      }
    }
    if (t < NT - 1) {
      if (t + 2 < NT) {
        // outstanding: A(t+1)4 + B(t+1)2 + A(t+2)4 -> leave A(t+2)
        asm volatile("s_waitcnt vmcnt(4)" ::: "memory");
      } else {
        asm volatile("s_waitcnt vmcnt(0)" ::: "memory");
      }
      __builtin_amdgcn_sched_barrier(0);
      __builtin_amdgcn_s_barrier();
      __builtin_amdgcn_sched_barrier(0);
    }
  }
#undef STAGE_A
#undef STAGE_B

#pragma unroll
  for (int m = 0; m < 4; ++m) {
#pragma unroll
    for (int n = 0; n < 2; ++n) {
      const int col = n0 + wc + n * 16 + l15;
      const float bb = bias[col];
#pragma unroll
      for (int e = 0; e < 4; ++e) {
        const int row = m0 + wr + m * 16 + l4 * 4 + e;
        float v = acc[m][n][e] + bb;
        if (EPI == 2) {
          v = 0.5f * v * (1.f + erff(v * 0.70710678118654752f));
        }
        outB[(size_t)row * N + col] = f2b(v);
      }
    }
  }
}

// ---------------------------------------------------------------------------
// Attention v6: r9/v5 structure with mask read DIRECT from global (int4,
// L2-hot) instead of an LDS maskadd array -> LDS = EXACTLY 65536 bytes
// -> 2 blocks/CU guaranteed. Everything else unchanged (flash-tiled, dbuf
// K/V staging, XCD-local b=bid&7, swizzles, T14 split).
// ---------------------------------------------------------------------------
__global__ __launch_bounds__(256, 2) void attn_kernel(
    const unsigned short* __restrict__ qkv, const int* __restrict__ mask,
    unsigned short* __restrict__ ctx) {
  extern __shared__ char smem[];
  const int bid = blockIdx.x;
  const int b = bid & 7, h = (bid >> 3) & 15, qt = bid >> 7;
  const int tid = threadIdx.x, l = tid & 63, w = tid >> 6;
  const int l15 = l & 15, l4 = l >> 4;
  const size_t RB = (size_t)b * 512 * 3072;
  const int* mrow = mask + b * 512;

  const unsigned short* Kbase = qkv + RB + 1024 + h * 64;
  const unsigned short* Vbase = qkv + RB + 2048 + h * 64;

  const int kr0 = tid >> 2, kc0 = tid & 3;
  const unsigned int swzk = (unsigned int)((kr0 & 7) << 4);
  const unsigned int ka0 = ((unsigned int)(kr0 * 128 + kc0 * 16)) ^ swzk;
  const unsigned int ka1 = ((unsigned int)(kr0 * 128 + kc0 * 16 + 64)) ^ swzk;
  const int vs0 = 2 * l, vd0 = w * 16;

  bf16x8 k00, k01, k10, k11, vreg[4];
  k00 = *(const bf16x8*)(Kbase + (size_t)kr0 * 3072 + kc0 * 8);
  k01 = *(const bf16x8*)(Kbase + (size_t)kr0 * 3072 + kc0 * 8 + 32);
  k10 = *(const bf16x8*)(Kbase + (size_t)(kr0 + 64) * 3072 + kc0 * 8);
  k11 = *(const bf16x8*)(Kbase + (size_t)(kr0 + 64) * 3072 + kc0 * 8 + 32);
  vreg[0] = *(const bf16x8*)(Vbase + (size_t)vs0 * 3072 + vd0);
  vreg[1] = *(const bf16x8*)(Vbase + (size_t)vs0 * 3072 + vd0 + 8);
  vreg[2] = *(const bf16x8*)(Vbase + (size_t)(vs0 + 1) * 3072 + vd0);
  vreg[3] = *(const bf16x8*)(Vbase + (size_t)(vs0 + 1) * 3072 + vd0 + 8);

  const int q0 = qt * 64 + w * 16;
  const unsigned short* qb =
      qkv + RB + (size_t)(q0 + l15) * 3072 + h * 64 + l4 * 8;
  const bf16x8 qf0 = *(const bf16x8*)(qb);
  const bf16x8 qf1 = *(const bf16x8*)(qb + 32);

#define KWRITE(dst)                        \
  {                                        \
    *(bf16x8*)((dst) + ka0) = k00;         \
    *(bf16x8*)((dst) + ka1) = k01;         \
    *(bf16x8*)((dst) + ka0 + 8192) = k10;  \
    *(bf16x8*)((dst) + ka1 + 8192) = k11;  \
  }
#define VWRITE(dst)                                                          \
  {                                                                          \
    _Pragma("unroll") for (int j = 0; j < 16; ++j) {                         \
      const unsigned short lo_ =                                             \
          (unsigned short)((j < 8) ? vreg[0][j] : vreg[1][j - 8]);           \
      const unsigned short hi_ =                                             \
          (unsigned short)((j < 8) ? vreg[2][j] : vreg[3][j - 8]);           \
      *(unsigned int*)((dst) +                                               \
                       (((vd0 + j) * 256 + vs0 * 2) ^ ((j & 7) << 4))) =     \
          (unsigned int)lo_ | ((unsigned int)hi_ << 16);                     \
    }                                                                        \
  }

  KWRITE(smem);
  VWRITE(smem + 32768);
  __syncthreads();

  const int hi4 = l4 >> 1, gl = l4 & 1, g2 = l4 & 2;
  f32x4 acc[4] = {};
  float run_m = -1e30f, run_s = 0.f;

#pragma unroll
  for (int t = 0; t < 4; ++t) {
    char* kcur = smem + (t & 1) * 16384;
    char* vcur = smem + 32768 + (t & 1) * 16384;
    if (t < 3) {
      const int sn = (t + 1) * 128;
      k00 = *(const bf16x8*)(Kbase + (size_t)(sn + kr0) * 3072 + kc0 * 8);
      k01 = *(const bf16x8*)(Kbase + (size_t)(sn + kr0) * 3072 + kc0 * 8 + 32);
      k10 = *(const bf16x8*)(Kbase + (size_t)(sn + kr0 + 64) * 3072 + kc0 * 8);
      k11 = *(const bf16x8*)(Kbase + (size_t)(sn + kr0 + 64) * 3072 + kc0 * 8 + 32);
      vreg[0] = *(const bf16x8*)(Vbase + (size_t)(sn + vs0) * 3072 + vd0);
      vreg[1] = *(const bf16x8*)(Vbase + (size_t)(sn + vs0) * 3072 + vd0 + 8);
      vreg[2] = *(const bf16x8*)(Vbase + (size_t)(sn + vs0 + 1) * 3072 + vd0);
      vreg[3] = *(const bf16x8*)(Vbase + (size_t)(sn + vs0 + 1) * 3072 + vd0 + 8);
      __builtin_amdgcn_sched_barrier(0);
    }
    f32x4 sc[8];
    __builtin_amdgcn_s_setprio(1);
#pragma unroll
    for (int kk = 0; kk < 8; ++kk) {
      const unsigned int lin = (unsigned int)((kk * 16 + l15) * 128 + l4 * 16);
      const unsigned int swz = (unsigned int)((l15 & 7) << 4);
      const bf16x8 af0 = *(const bf16x8*)(kcur + (lin ^ swz));
      const bf16x8 af1 = *(const bf16x8*)(kcur + ((lin + 64) ^ swz));
      f32x4 c = {0.f, 0.f, 0.f, 0.f};
      c = MFMA16(af0, qf0, c);
      c = MFMA16(af1, qf1, c);
      sc[kk] = c;
    }
    __builtin_amdgcn_s_setprio(0);
    float tmx = -1e30f;
#pragma unroll
    for (int kk = 0; kk < 8; ++kk) {
      const int4 mv = *(const int4*)(mrow + t * 128 + kk * 16 + l4 * 4);
      sc[kk][0] += mv.x ? 0.f : -1e18f;
      sc[kk][1] += mv.y ? 0.f : -1e18f;
      sc[kk][2] += mv.z ? 0.f : -1e18f;
      sc[kk][3] += mv.w ? 0.f : -1e18f;
#pragma unroll
      for (int e = 0; e < 4; ++e) tmx = fmaxf(tmx, sc[kk][e]);
    }
    tmx = fmaxf(tmx, __shfl_xor(tmx, 16));
    tmx = fmaxf(tmx, __shfl_xor(tmx, 32));
    const float nm = (t == 0) ? tmx : fmaxf(run_m, tmx);
    float tsum = 0.f;
    unsigned int pk[8][2];
#pragma unroll
    for (int kk = 0; kk < 8; ++kk) {
      const float p0 = __expf(sc[kk][0] - nm);
      const float p1 = __expf(sc[kk][1] - nm);
      const float p2 = __expf(sc[kk][2] - nm);
      const float p3 = __expf(sc[kk][3] - nm);
      tsum += (p0 + p1) + (p2 + p3);
      asm("v_cvt_pk_bf16_f32 %0, %1, %2" : "=v"(pk[kk][0]) : "v"(p0), "v"(p1));
      asm("v_cvt_pk_bf16_f32 %0, %1, %2" : "=v"(pk[kk][1]) : "v"(p2), "v"(p3));
    }
    tsum += __shfl_xor(tsum, 16);
    tsum += __shfl_xor(tsum, 32);
    if (t == 0) {
      run_s = tsum;
    } else {
      const float scale = __expf(run_m - nm);
      run_s = run_s * scale + tsum;
      float s4[4];
#pragma unroll
      for (int e = 0; e < 4; ++e) s4[e] = __shfl(scale, l4 * 4 + e);
#pragma unroll
      for (int nt = 0; nt < 4; ++nt) {
#pragma unroll
        for (int e = 0; e < 4; ++e) acc[nt][e] *= s4[e];
      }
    }
    run_m = nm;
#pragma unroll
    for (int k2 = 0; k2 < 4; ++k2) {
      const unsigned int own0 = hi4 ? pk[2 * k2 + 1][0] : pk[2 * k2][0];
      const unsigned int own1 = hi4 ? pk[2 * k2 + 1][1] : pk[2 * k2][1];
      const unsigned int oth0 = hi4 ? pk[2 * k2][0] : pk[2 * k2 + 1][0];
      const unsigned int oth1 = hi4 ? pk[2 * k2][1] : pk[2 * k2 + 1][1];
      const unsigned int s16_0 = (unsigned int)__shfl_xor((int)own0, 16);
      const unsigned int s16_1 = (unsigned int)__shfl_xor((int)own1, 16);
      const unsigned int s32_0 = (unsigned int)__shfl_xor((int)oth0, 32);
      const unsigned int s32_1 = (unsigned int)__shfl_xor((int)oth1, 32);
      const unsigned int s48_0 = (unsigned int)__shfl_xor((int)oth0, 48);
      const unsigned int s48_1 = (unsigned int)__shfl_xor((int)oth1, 48);
      union { unsigned int u[4]; bf16x8 v; } pa;
      pa.u[0] = g2 ? (gl ? s16_0 : s32_0) : (gl ? s48_0 : own0);
      pa.u[1] = g2 ? (gl ? s16_1 : s32_1) : (gl ? s48_1 : own1);
      pa.u[2] = g2 ? (gl ? own0 : s48_0) : (gl ? s32_0 : s16_0);
      pa.u[3] = g2 ? (gl ? own1 : s48_1) : (gl ? s32_1 : s16_1);
      __builtin_amdgcn_s_setprio(1);
#pragma unroll
      for (int nt = 0; nt < 4; ++nt) {
        const int d = nt * 16 + l15;
        const unsigned int vb =
            (unsigned int)((d * 256 + k2 * 64 + l4 * 16) ^ ((l15 & 7) << 4));
        const bf16x8 vbf = *(const bf16x8*)(vcur + vb);
        acc[nt] = MFMA16(pa.v, vbf, acc[nt]);
      }
      __builtin_amdgcn_s_setprio(0);
    }
    if (t < 3) {
      char* knxt = smem + ((t + 1) & 1) * 16384;
      char* vnxt = smem + 32768 + ((t + 1) & 1) * 16384;
      KWRITE(knxt);
      VWRITE(vnxt);
      __syncthreads();
    }
  }
#undef KWRITE
#undef VWRITE

  const float inv = 1.f / run_s;
  float invq[4];
#pragma unroll
  for (int e = 0; e < 4; ++e) invq[e] = __shfl(inv, l4 * 4 + e);
#pragma unroll
  for (int nt = 0; nt < 4; ++nt) {
#pragma unroll
    for (int e = 0; e < 4; ++e) {
      const size_t row = (size_t)b * 512 + q0 + l4 * 4 + e;
      ctx[row * 1024 + h * 64 + nt * 16 + l15] = f2b(acc[nt][e] * invq[e]);
    }
  }
}

// ---------------------------------------------------------------------------
// Custom LayerNorm (unbiased std, eps added to std). One block per row.
// MODE 0: A f32, no residual, +PE, out bf16.
// MODE 1: A bf16, R bf16, out bf16.
// MODE 2: A bf16, R bf16, out f32.
// ---------------------------------------------------------------------------
template <int MODE>
__global__ __launch_bounds__(256) void ln_k(
    const void* __restrict__ Ap, const void* __restrict__ Rp,
    const float* __restrict__ g, const float* __restrict__ bta,
    void* __restrict__ outp) {
  __shared__ float red[8];
  const int row = blockIdx.x, tid = threadIdx.x;
  const size_t base = (size_t)row * 1024 + tid * 4;
  float a4[4];
  if (MODE == 0) {
    const float4 a = *(const float4*)((const float*)Ap + base);
    a4[0] = a.x; a4[1] = a.y; a4[2] = a.z; a4[3] = a.w;
  } else {
    const bf16x4 a = *(const bf16x4*)((const unsigned short*)Ap + base);
    const bf16x4 rr = *(const bf16x4*)((const unsigned short*)Rp + base);
#pragma unroll
    for (int j = 0; j < 4; ++j)
      a4[j] = b2f((unsigned short)a[j]) + b2f((unsigned short)rr[j]);
  }
  float s = a4[0] + a4[1] + a4[2] + a4[3];
  float q = a4[0] * a4[0] + a4[1] * a4[1] + a4[2] * a4[2] + a4[3] * a4[3];
#pragma unroll
  for (int o = 32; o; o >>= 1) {
    s += __shfl_xor(s, o);
    q += __shfl_xor(q, o);
  }
  if ((tid & 63) == 0) {
    red[(tid >> 6) * 2] = s;
    red[(tid >> 6) * 2 + 1] = q;
  }
  __syncthreads();
  const float S = red[0] + red[2] + red[4] + red[6];
  const float Qs = red[1] + red[3] + red[5] + red[7];
  const float mean = S * (1.f / 1024.f);
  float var = (Qs - 1024.f * mean * mean) * (1.f / 1023.f);
  var = fmaxf(var, 0.f);
  const float inv = 1.f / (sqrtf(var) + 1e-6f);
  float o4[4];
#pragma unroll
  for (int j = 0; j < 4; ++j) {
    const int col = tid * 4 + j;
    float y = g[col] * (a4[j] - mean) * inv + bta[col];
    if (MODE == 0) {
      const float ang =
          (float)(row & 511) * exp2f((float)col * -0.025952563241307518f);
      y += (col & 1) ? cosf(ang) : sinf(ang);
    }
    o4[j] = y;
  }
  if (MODE == 2) {
    *(float4*)((float*)outp + base) = make_float4(o4[0], o4[1], o4[2], o4[3]);
  } else {
    bf16x4 pb;
    pb[0] = (short)f2b(o4[0]);
    pb[1] = (short)f2b(o4[1]);
    pb[2] = (short)f2b(o4[2]);
    pb[3] = (short)f2b(o4[3]);
    *(bf16x4*)((unsigned short*)outp + base) = pb;
  }
}

// ---------------------------------------------------------------------------
// Fused weight prep: 6 f32->bf16 matrix converts + QKV bias pack, one launch.
// ---------------------------------------------------------------------------
__global__ __launch_bounds__(256) void prep_weights(
    const float* __restrict__ Wq, const float* __restrict__ Wk,
    const float* __restrict__ Wv, const float* __restrict__ Wo,
    const float* __restrict__ W1, const float* __restrict__ W2,
    const float* __restrict__ bq, const float* __restrict__ bk,
    const float* __restrict__ bv, unsigned short* __restrict__ wqkv,
    unsigned short* __restrict__ wo, unsigned short* __restrict__ w1,
    unsigned short* __restrict__ w2, float* __restrict__ bqkv) {
  const int gid = blockIdx.x * 256 + threadIdx.x;
  if (gid < 1572864) {
    const int chunk = gid >> 18;
    const int off = (gid & 262143) * 4;
    const float* s;
    unsigned short* d;
    switch (chunk) {
      case 0: s = Wq; d = wqkv; break;
      case 1: s = Wk; d = wqkv + 1048576; break;
      case 2: s = Wv; d = wqkv + 2097152; break;
      case 3: s = Wo; d = wo; break;
      case 4: s = W1; d = w1; break;
      default: s = W2; d = w2; break;
    }
    const float4 v = *(const float4*)(s + off);
    bf16x4 o;
    o[0] = (short)f2b(v.x); o[1] = (short)f2b(v.y);
    o[2] = (short)f2b(v.z); o[3] = (short)f2b(v.w);
    *(bf16x4*)(d + off) = o;
  } else {
    const int idx = (gid - 1572864) * 4;
    if (idx < 3072) {
      const float* bs = idx < 1024 ? bq : (idx < 2048 ? bk - 1024 : bv - 2048);
      *(float4*)(bqkv + idx) = *(const float4*)(bs + idx);
    }
  }
}

extern "C" void kernel_launch(void* const* d_in, const int* in_sizes, int n_in,
                              void* d_out, int out_size, void* d_ws, size_t ws_size,
                              hipStream_t stream) {
  (void)in_sizes; (void)n_in; (void)out_size; (void)ws_size;
  const float* features = (const float*)d_in[0];
  const int* mask = (const int*)d_in[1];
  const float* ln_in_g = (const float*)d_in[2];
  const float* ln_in_b = (const float*)d_in[3];
  const size_t DD = 1024 * 1024;
  // layer index 1 (the only live layer)
  const float* Wq = (const float*)d_in[4] + DD;
  const float* bq = (const float*)d_in[5] + 1024;
  const float* Wk = (const float*)d_in[6] + DD;
  const float* bk = (const float*)d_in[7] + 1024;
  const float* Wv = (const float*)d_in[8] + DD;
  const float* bv = (const float*)d_in[9] + 1024;
  const float* Wo = (const float*)d_in[10] + DD;
  const float* bo = (const float*)d_in[11] + 1024;
  const float* l1g = (const float*)d_in[12] + 1024;
  const float* l1b = (const float*)d_in[13] + 1024;
  const float* W1 = (const float*)d_in[14] + DD;
  const float* b1 = (const float*)d_in[15] + 1024;
  const float* W2 = (const float*)d_in[16] + DD;
  const float* b2 = (const float*)d_in[17] + 1024;
  const float* l2g = (const float*)d_in[18] + 1024;
  const float* l2b = (const float*)d_in[19] + 1024;

  char* base = (char*)d_ws;
  unsigned short* qkv = (unsigned short*)(base);              // 24 MB [4096][3072]
  unsigned short* xb = (unsigned short*)(base + 25165824);    // 8 MB: x bf16, then h
  unsigned short* ctxb = (unsigned short*)(base + 33554432);  // 8 MB: ctx, then s
  unsigned short* abuf = (unsigned short*)(base + 41943040);  // 8 MB: attn_out, then f
  unsigned short* wqkv = (unsigned short*)(base + 50331648);  // 6 MB [3072][1024]
  unsigned short* wo = (unsigned short*)(base + 56623104);    // 2 MB
  unsigned short* w1 = (unsigned short*)(base + 58720256);    // 2 MB
  unsigned short* w2 = (unsigned short*)(base + 60817408);    // 2 MB
  float* bqkv = (float*)(base + 62914560);                    // 12 KB

  hipFuncSetAttribute((const void*)gemm_qkv,
                      hipFuncAttributeMaxDynamicSharedMemorySize, 98304);
  hipFuncSetAttribute((const void*)attn_kernel,
                      hipFuncAttributeMaxDynamicSharedMemorySize, 65536);

  prep_weights<<<6147, 256, 0, stream>>>(Wq, Wk, Wv, Wo, W1, W2, bq, bk, bv,
                                         wqkv, wo, w1, w2, bqkv);
  // x = LN(features) + PE -> bf16
  ln_k<0><<<4096, 256, 0, stream>>>(features, nullptr, ln_in_g, ln_in_b, xb);
  // fused QKV projection (Q pre-scaled by 1/8): 32m x 24n = 768 blocks
  gemm_qkv<<<768, 256, 98304, stream>>>(xb, wqkv, bqkv, qkv, 3072, 1024, 12);
  // attention
  attn_kernel<<<1024, 256, 65536, stream>>>(qkv, mask, ctxb);
  // attn_out = ctx @ Wo^T + bo -> bf16 : 32m x 16n = 512 blocks
  gemm_s<3><<<512, 256, 0, stream>>>(ctxb, wo, bo, abuf, 1024, 8);
  // s = LN(attn_out + x) -> bf16 (overwrites ctx)
  ln_k<1><<<4096, 256, 0, stream>>>(abuf, xb, l1g, l1b, ctxb);
  // h = gelu(s @ W1^T + b1) -> bf16 (overwrites x)
  gemm_s<2><<<512, 256, 0, stream>>>(ctxb, w1, b1, xb, 1024, 8);
  // f = h @ W2^T + b2 -> bf16 (overwrites attn_out)
  gemm_s<3><<<512, 256, 0, stream>>>(xb, w2, b2, abuf, 1024, 8);
  // out = LN(f + s) -> f32
  ln_k<2><<<4096, 256, 0, stream>>>(abuf, ctxb, l2g, l2b, (float*)d_out);
}

// Round 15
// 152.931 us; speedup vs baseline: 1.1093x; 1.0743x over previous
//
#include <hip/hip_runtime.h>
#include <cstdint>
#include <cstddef>

// Only layer i=1 is live (reference loop re-reads x, so layer 0 is dead code).
// B=8, S=512, D=1024, H=16, DH=64. All GEMMs are M=4096, K=1024.
// All intermediates bf16; only final LN writes f32.
// Config = r9 (e2e-best 155.0) + prep/LN0 fusion (r13-verified).
// Mapped-and-rejected: B-in-reg (r10), 64KB-static 2blk/CU (r11/r14, B-depth
// 3 > occupancy 2), fat wave tile (r12), split-K (r13), mask-direct (r14).

typedef __attribute__((ext_vector_type(8))) short bf16x8;
typedef __attribute__((ext_vector_type(4))) short bf16x4;
typedef __attribute__((ext_vector_type(4))) float f32x4;

#define MFMA16(a, b, c) __builtin_amdgcn_mfma_f32_16x16x32_bf16((a), (b), (c), 0, 0, 0)

__device__ __forceinline__ unsigned short f2b(float f) {
  union { float f; unsigned int u; } x; x.f = f;
  unsigned int r = x.u + 0x7fffu + ((x.u >> 16) & 1u);
  return (unsigned short)(r >> 16);
}

__device__ __forceinline__ float b2f(unsigned short u) {
  union { unsigned int i; float f; } x;
  x.i = ((unsigned int)u) << 16;
  return x.f;
}

__device__ __forceinline__ void gl_lds16(const void* g, void* l) {
  __builtin_amdgcn_global_load_lds(
      (const __attribute__((address_space(1))) void*)g,
      (__attribute__((address_space(3))) void*)l, 16, 0, 0);
}

// ---------------------------------------------------------------------------
// GEMM (r9 structure verbatim): BM=128, BK=64, BN templated. 3-deep pipelined
// staging for BOTH A and B, COUNTED vmcnt, raw s_barrier once per K-step,
// vmcnt(0) only at tail. Pre-swizzled global source (conflict-free).
// EPI: 1 = +bias, cols<1024 scaled 1/8; 2 = GELU; 3 = +bias. All -> bf16.
// 1D grid, bijective XCD mapping: xcd=bid&7 owns an 8m x nnHalf region.
// ---------------------------------------------------------------------------
template <int BN, int EPI>
__global__ __launch_bounds__(256) void gemm_t(
    const unsigned short* __restrict__ A, const unsigned short* __restrict__ B,
    const float* __restrict__ bias, unsigned short* __restrict__ outB, int N,
    int K, int nnHalf) {
  extern __shared__ char smem[];
  char* la = smem;              // 3 x [128 rows][128 B]
  char* lb = smem + 3 * 16384;  // 3 x [BN rows][128 B]
  constexpr int NR = BN / 32;
  const int tid = threadIdx.x;
  const int l = tid & 63, w = tid >> 6;
  const int l15 = l & 15, l4 = l >> 4;
  const int xcd = blockIdx.x & 7, r = blockIdx.x >> 3;
  const int m0 = ((xcd >> 1) * 8 + (r & 7)) * 128;
  const int n0 = ((xcd & 1) * nnHalf + (r >> 3)) * BN;
  const int wr = (w >> 1) * 64, wc = (w & 1) * (BN / 2);
  const int NT = K >> 6;  // K-steps of 64

#define STAGE(buf, t)                                                         \
  {                                                                           \
    const int k0_ = (t) * 64;                                                 \
    _Pragma("unroll") for (int i = 0; i < 4; ++i) {                           \
      const int c = i * 256 + tid;                                            \
      const int row = c >> 3;                                                 \
      const int gch = (c & 7) ^ (row & 7);                                    \
      gl_lds16(A + (size_t)(m0 + row) * K + k0_ + gch * 8,                    \
               la + (buf) * 16384 + (i * 256 + w * 64) * 16);                 \
    }                                                                         \
    _Pragma("unroll") for (int i = 0; i < BN / 32; ++i) {                     \
      const int c = i * 256 + tid;                                            \
      const int row = c >> 3;                                                 \
      const int gch = (c & 7) ^ (row & 7);                                    \
      gl_lds16(B + (size_t)(n0 + row) * K + k0_ + gch * 8,                    \
               lb + (buf) * (BN * 128) + (i * 256 + w * 64) * 16);            \
    }                                                                         \
  }
#define WAIT_L()                                                   \
  {                                                                \
    if constexpr (BN == 128) {                                     \
      asm volatile("s_waitcnt vmcnt(8)" ::: "memory");             \
    } else {                                                       \
      asm volatile("s_waitcnt vmcnt(6)" ::: "memory");             \
    }                                                              \
  }

  f32x4 acc[4][NR] = {};
  const int sw = l15 & 7;

  STAGE(0, 0);
  STAGE(1, 1);
  WAIT_L();  // tile 0 landed (tile 1 still in flight)
  __builtin_amdgcn_sched_barrier(0);
  __builtin_amdgcn_s_barrier();
  __builtin_amdgcn_sched_barrier(0);

  for (int t = 0; t < NT; ++t) {
    if (t + 2 < NT) {
      STAGE((t + 2) % 3, t + 2);
    }
    __builtin_amdgcn_sched_barrier(0);
    const char* abuf = la + (t % 3) * 16384;
    const char* bbuf = lb + (t % 3) * (BN * 128);
#pragma unroll
    for (int kk = 0; kk < 2; ++kk) {
      const unsigned int ch = (unsigned int)(((kk * 4 + l4) ^ sw) << 4);
      bf16x8 af[4], bfr[NR];
#pragma unroll
      for (int m = 0; m < 4; ++m)
        af[m] = *(const bf16x8*)(abuf + (wr + m * 16 + l15) * 128 + ch);
#pragma unroll
      for (int n = 0; n < NR; ++n)
        bfr[n] = *(const bf16x8*)(bbuf + (wc + n * 16 + l15) * 128 + ch);
#pragma unroll
      for (int m = 0; m < 4; ++m) {
#pragma unroll
        for (int n = 0; n < NR; ++n) {
          acc[m][n] = MFMA16(af[m], bfr[n], acc[m][n]);
        }
      }
    }
    if (t < NT - 1) {
      if (t + 2 < NT) {
        WAIT_L();  // tile t+1 landed; tile t+2 still in flight
      } else {
        asm volatile("s_waitcnt vmcnt(0)" ::: "memory");  // tail drain
      }
      __builtin_amdgcn_sched_barrier(0);
      __builtin_amdgcn_s_barrier();
      __builtin_amdgcn_sched_barrier(0);
    }
  }
#undef STAGE
#undef WAIT_L

#pragma unroll
  for (int m = 0; m < 4; ++m) {
#pragma unroll
    for (int n = 0; n < NR; ++n) {
      const int col = n0 + wc + n * 16 + l15;
      const float bb = bias[col];
#pragma unroll
      for (int e = 0; e < 4; ++e) {
        const int row = m0 + wr + m * 16 + l4 * 4 + e;
        float v = acc[m][n][e] + bb;
        if (EPI == 1) {
          if (col < 1024) v *= 0.125f;  // fold 1/sqrt(DH) into Q
        } else if (EPI == 2) {
          v = 0.5f * v * (1.f + erff(v * 0.70710678118654752f));
        }
        outB[(size_t)row * N + col] = f2b(v);
      }
    }
  }
}

// ---------------------------------------------------------------------------
// Attention (r9/v5 verbatim, passing): flash-tiled, double-buffered LDS
// staging of K AND V, XCD-local b=bid&7 mapping, swizzled K/V^T, T14 split,
// LDS maskadd (prefetched once — direct-global variant cost ~6us, r14).
// ---------------------------------------------------------------------------
__global__ __launch_bounds__(256, 2) void attn_kernel(
    const unsigned short* __restrict__ qkv, const int* __restrict__ mask,
    unsigned short* __restrict__ ctx) {
  extern __shared__ char smem[];
  float* maskadd = (float*)(smem + 65536);  // [512]
  const int bid = blockIdx.x;
  const int b = bid & 7, h = (bid >> 3) & 15, qt = bid >> 7;
  const int tid = threadIdx.x, l = tid & 63, w = tid >> 6;
  const int l15 = l & 15, l4 = l >> 4;
  const size_t RB = (size_t)b * 512 * 3072;

  for (int s = tid; s < 512; s += 256)
    maskadd[s] = mask[b * 512 + s] ? 0.f : -1e18f;

  const unsigned short* Kbase = qkv + RB + 1024 + h * 64;
  const unsigned short* Vbase = qkv + RB + 2048 + h * 64;

  const int kr0 = tid >> 2, kc0 = tid & 3;
  const unsigned int swzk = (unsigned int)((kr0 & 7) << 4);
  const unsigned int ka0 = ((unsigned int)(kr0 * 128 + kc0 * 16)) ^ swzk;
  const unsigned int ka1 = ((unsigned int)(kr0 * 128 + kc0 * 16 + 64)) ^ swzk;
  const int vs0 = 2 * l, vd0 = w * 16;

  bf16x8 k00, k01, k10, k11, vreg[4];
  k00 = *(const bf16x8*)(Kbase + (size_t)kr0 * 3072 + kc0 * 8);
  k01 = *(const bf16x8*)(Kbase + (size_t)kr0 * 3072 + kc0 * 8 + 32);
  k10 = *(const bf16x8*)(Kbase + (size_t)(kr0 + 64) * 3072 + kc0 * 8);
  k11 = *(const bf16x8*)(Kbase + (size_t)(kr0 + 64) * 3072 + kc0 * 8 + 32);
  vreg[0] = *(const bf16x8*)(Vbase + (size_t)vs0 * 3072 + vd0);
  vreg[1] = *(const bf16x8*)(Vbase + (size_t)vs0 * 3072 + vd0 + 8);
  vreg[2] = *(const bf16x8*)(Vbase + (size_t)(vs0 + 1) * 3072 + vd0);
  vreg[3] = *(const bf16x8*)(Vbase + (size_t)(vs0 + 1) * 3072 + vd0 + 8);

  const int q0 = qt * 64 + w * 16;
  const unsigned short* qb =
      qkv + RB + (size_t)(q0 + l15) * 3072 + h * 64 + l4 * 8;
  const bf16x8 qf0 = *(const bf16x8*)(qb);
  const bf16x8 qf1 = *(const bf16x8*)(qb + 32);

#define KWRITE(dst)                        \
  {                                        \
    *(bf16x8*)((dst) + ka0) = k00;         \
    *(bf16x8*)((dst) + ka1) = k01;         \
    *(bf16x8*)((dst) + ka0 + 8192) = k10;  \
    *(bf16x8*)((dst) + ka1 + 8192) = k11;  \
  }
#define VWRITE(dst)                                                          \
  {                                                                          \
    _Pragma("unroll") for (int j = 0; j < 16; ++j) {                         \
      const unsigned short lo_ =                                             \
          (unsigned short)((j < 8) ? vreg[0][j] : vreg[1][j - 8]);           \
      const unsigned short hi_ =                                             \
          (unsigned short)((j < 8) ? vreg[2][j] : vreg[3][j - 8]);           \
      *(unsigned int*)((dst) +                                               \
                       (((vd0 + j) * 256 + vs0 * 2) ^ ((j & 7) << 4))) =     \
          (unsigned int)lo_ | ((unsigned int)hi_ << 16);                     \
    }                                                                        \
  }

  KWRITE(smem);
  VWRITE(smem + 32768);
  __syncthreads();

  const int hi4 = l4 >> 1, gl = l4 & 1, g2 = l4 & 2;
  f32x4 acc[4] = {};
  float run_m = -1e30f, run_s = 0.f;

#pragma unroll
  for (int t = 0; t < 4; ++t) {
    char* kcur = smem + (t & 1) * 16384;
    char* vcur = smem + 32768 + (t & 1) * 16384;
    if (t < 3) {
      const int sn = (t + 1) * 128;
      k00 = *(const bf16x8*)(Kbase + (size_t)(sn + kr0) * 3072 + kc0 * 8);
      k01 = *(const bf16x8*)(Kbase + (size_t)(sn + kr0) * 3072 + kc0 * 8 + 32);
      k10 = *(const bf16x8*)(Kbase + (size_t)(sn + kr0 + 64) * 3072 + kc0 * 8);
      k11 = *(const bf16x8*)(Kbase + (size_t)(sn + kr0 + 64) * 3072 + kc0 * 8 + 32);
      vreg[0] = *(const bf16x8*)(Vbase + (size_t)(sn + vs0) * 3072 + vd0);
      vreg[1] = *(const bf16x8*)(Vbase + (size_t)(sn + vs0) * 3072 + vd0 + 8);
      vreg[2] = *(const bf16x8*)(Vbase + (size_t)(sn + vs0 + 1) * 3072 + vd0);
      vreg[3] = *(const bf16x8*)(Vbase + (size_t)(sn + vs0 + 1) * 3072 + vd0 + 8);
      __builtin_amdgcn_sched_barrier(0);
    }
    f32x4 sc[8];
    __builtin_amdgcn_s_setprio(1);
#pragma unroll
    for (int kk = 0; kk < 8; ++kk) {
      const unsigned int lin = (unsigned int)((kk * 16 + l15) * 128 + l4 * 16);
      const unsigned int swz = (unsigned int)((l15 & 7) << 4);
      const bf16x8 af0 = *(const bf16x8*)(kcur + (lin ^ swz));
      const bf16x8 af1 = *(const bf16x8*)(kcur + ((lin + 64) ^ swz));
      f32x4 c = {0.f, 0.f, 0.f, 0.f};
      c = MFMA16(af0, qf0, c);
      c = MFMA16(af1, qf1, c);
      sc[kk] = c;
    }
    __builtin_amdgcn_s_setprio(0);
    float tmx = -1e30f;
#pragma unroll
    for (int kk = 0; kk < 8; ++kk) {
#pragma unroll
      for (int e = 0; e < 4; ++e) {
        const float v = sc[kk][e] + maskadd[t * 128 + kk * 16 + l4 * 4 + e];
        sc[kk][e] = v;
        tmx = fmaxf(tmx, v);
      }
    }
    tmx = fmaxf(tmx, __shfl_xor(tmx, 16));
    tmx = fmaxf(tmx, __shfl_xor(tmx, 32));
    const float nm = (t == 0) ? tmx : fmaxf(run_m, tmx);
    float tsum = 0.f;
    unsigned int pk[8][2];
#pragma unroll
    for (int kk = 0; kk < 8; ++kk) {
      const float p0 = __expf(sc[kk][0] - nm);
      const float p1 = __expf(sc[kk][1] - nm);
      const float p2 = __expf(sc[kk][2] - nm);
      const float p3 = __expf(sc[kk][3] - nm);
      tsum += (p0 + p1) + (p2 + p3);
      asm("v_cvt_pk_bf16_f32 %0, %1, %2" : "=v"(pk[kk][0]) : "v"(p0), "v"(p1));
      asm("v_cvt_pk_bf16_f32 %0, %1, %2" : "=v"(pk[kk][1]) : "v"(p2), "v"(p3));
    }
    tsum += __shfl_xor(tsum, 16);
    tsum += __shfl_xor(tsum, 32);
    if (t == 0) {
      run_s = tsum;
    } else {
      const float scale = __expf(run_m - nm);
      run_s = run_s * scale + tsum;
      float s4[4];
#pragma unroll
      for (int e = 0; e < 4; ++e) s4[e] = __shfl(scale, l4 * 4 + e);
#pragma unroll
      for (int nt = 0; nt < 4; ++nt) {
#pragma unroll
        for (int e = 0; e < 4; ++e) acc[nt][e] *= s4[e];
      }
    }
    run_m = nm;
#pragma unroll
    for (int k2 = 0; k2 < 4; ++k2) {
      const unsigned int own0 = hi4 ? pk[2 * k2 + 1][0] : pk[2 * k2][0];
      const unsigned int own1 = hi4 ? pk[2 * k2 + 1][1] : pk[2 * k2][1];
      const unsigned int oth0 = hi4 ? pk[2 * k2][0] : pk[2 * k2 + 1][0];
      const unsigned int oth1 = hi4 ? pk[2 * k2][1] : pk[2 * k2 + 1][1];
      const unsigned int s16_0 = (unsigned int)__shfl_xor((int)own0, 16);
      const unsigned int s16_1 = (unsigned int)__shfl_xor((int)own1, 16);
      const unsigned int s32_0 = (unsigned int)__shfl_xor((int)oth0, 32);
      const unsigned int s32_1 = (unsigned int)__shfl_xor((int)oth1, 32);
      const unsigned int s48_0 = (unsigned int)__shfl_xor((int)oth0, 48);
      const unsigned int s48_1 = (unsigned int)__shfl_xor((int)oth1, 48);
      union { unsigned int u[4]; bf16x8 v; } pa;
      pa.u[0] = g2 ? (gl ? s16_0 : s32_0) : (gl ? s48_0 : own0);
      pa.u[1] = g2 ? (gl ? s16_1 : s32_1) : (gl ? s48_1 : own1);
      pa.u[2] = g2 ? (gl ? own0 : s48_0) : (gl ? s32_0 : s16_0);
      pa.u[3] = g2 ? (gl ? own1 : s48_1) : (gl ? s32_1 : s16_1);
      __builtin_amdgcn_s_setprio(1);
#pragma unroll
      for (int nt = 0; nt < 4; ++nt) {
        const int d = nt * 16 + l15;
        const unsigned int vb =
            (unsigned int)((d * 256 + k2 * 64 + l4 * 16) ^ ((l15 & 7) << 4));
        const bf16x8 vbf = *(const bf16x8*)(vcur + vb);
        acc[nt] = MFMA16(pa.v, vbf, acc[nt]);
      }
      __builtin_amdgcn_s_setprio(0);
    }
    if (t < 3) {
      char* knxt = smem + ((t + 1) & 1) * 16384;
      char* vnxt = smem + 32768 + ((t + 1) & 1) * 16384;
      KWRITE(knxt);
      VWRITE(vnxt);
      __syncthreads();
    }
  }
#undef KWRITE
#undef VWRITE

  const float inv = 1.f / run_s;
  float invq[4];
#pragma unroll
  for (int e = 0; e < 4; ++e) invq[e] = __shfl(inv, l4 * 4 + e);
#pragma unroll
  for (int nt = 0; nt < 4; ++nt) {
#pragma unroll
    for (int e = 0; e < 4; ++e) {
      const size_t row = (size_t)b * 512 + q0 + l4 * 4 + e;
      ctx[row * 1024 + h * 64 + nt * 16 + l15] = f2b(acc[nt][e] * invq[e]);
    }
  }
}

// ---------------------------------------------------------------------------
// Custom LayerNorm (unbiased std, eps added to std). One block per row.
// MODE 1: A bf16, R bf16, out bf16.  MODE 2: A bf16, R bf16, out f32.
// ---------------------------------------------------------------------------
template <int MODE>
__global__ __launch_bounds__(256) void ln_k(
    const void* __restrict__ Ap, const void* __restrict__ Rp,
    const float* __restrict__ g, const float* __restrict__ bta,
    void* __restrict__ outp) {
  __shared__ float red[8];
  const int row = blockIdx.x, tid = threadIdx.x;
  const size_t base = (size_t)row * 1024 + tid * 4;
  float a4[4];
  {
    const bf16x4 a = *(const bf16x4*)((const unsigned short*)Ap + base);
    const bf16x4 rr = *(const bf16x4*)((const unsigned short*)Rp + base);
#pragma unroll
    for (int j = 0; j < 4; ++j)
      a4[j] = b2f((unsigned short)a[j]) + b2f((unsigned short)rr[j]);
  }
  float s = a4[0] + a4[1] + a4[2] + a4[3];
  float q = a4[0] * a4[0] + a4[1] * a4[1] + a4[2] * a4[2] + a4[3] * a4[3];
#pragma unroll
  for (int o = 32; o; o >>= 1) {
    s += __shfl_xor(s, o);
    q += __shfl_xor(q, o);
  }
  if ((tid & 63) == 0) {
    red[(tid >> 6) * 2] = s;
    red[(tid >> 6) * 2 + 1] = q;
  }
  __syncthreads();
  const float S = red[0] + red[2] + red[4] + red[6];
  const float Qs = red[1] + red[3] + red[5] + red[7];
  const float mean = S * (1.f / 1024.f);
  float var = (Qs - 1024.f * mean * mean) * (1.f / 1023.f);
  var = fmaxf(var, 0.f);
  const float inv = 1.f / (sqrtf(var) + 1e-6f);
  if (MODE == 2) {
    float4 o4;
    o4.x = g[tid * 4 + 0] * (a4[0] - mean) * inv + bta[tid * 4 + 0];
    o4.y = g[tid * 4 + 1] * (a4[1] - mean) * inv + bta[tid * 4 + 1];
    o4.z = g[tid * 4 + 2] * (a4[2] - mean) * inv + bta[tid * 4 + 2];
    o4.w = g[tid * 4 + 3] * (a4[3] - mean) * inv + bta[tid * 4 + 3];
    *(float4*)((float*)outp + base) = o4;
  } else {
    bf16x4 pb;
#pragma unroll
    for (int j = 0; j < 4; ++j) {
      const int col = tid * 4 + j;
      pb[j] = (short)f2b(g[col] * (a4[j] - mean) * inv + bta[col]);
    }
    *(bf16x4*)((unsigned short*)outp + base) = pb;
  }
}

// ---------------------------------------------------------------------------
// Fused (r13-verified): input LN (+PE) for blocks < 4096; weight f32->bf16
// convert + QKV bias pack for the rest. One dispatch instead of two.
// ---------------------------------------------------------------------------
__global__ __launch_bounds__(256) void prep_ln(
    const float* __restrict__ features, const float* __restrict__ g,
    const float* __restrict__ bta, unsigned short* __restrict__ xb,
    const float* __restrict__ Wq, const float* __restrict__ Wk,
    const float* __restrict__ Wv, const float* __restrict__ Wo,
    const float* __restrict__ W1, const float* __restrict__ W2,
    const float* __restrict__ bq, const float* __restrict__ bk,
    const float* __restrict__ bv, unsigned short* __restrict__ wqkv,
    unsigned short* __restrict__ wo, unsigned short* __restrict__ w1,
    unsigned short* __restrict__ w2, float* __restrict__ bqkv) {
  if (blockIdx.x < 4096) {
    __shared__ float red[8];
    const int row = blockIdx.x, tid = threadIdx.x;
    const size_t base = (size_t)row * 1024 + tid * 4;
    const float4 a = *(const float4*)(features + base);
    float a4[4] = {a.x, a.y, a.z, a.w};
    float s = a4[0] + a4[1] + a4[2] + a4[3];
    float q = a4[0] * a4[0] + a4[1] * a4[1] + a4[2] * a4[2] + a4[3] * a4[3];
#pragma unroll
    for (int o = 32; o; o >>= 1) {
      s += __shfl_xor(s, o);
      q += __shfl_xor(q, o);
    }
    if ((tid & 63) == 0) {
      red[(tid >> 6) * 2] = s;
      red[(tid >> 6) * 2 + 1] = q;
    }
    __syncthreads();
    const float S = red[0] + red[2] + red[4] + red[6];
    const float Qs = red[1] + red[3] + red[5] + red[7];
    const float mean = S * (1.f / 1024.f);
    float var = (Qs - 1024.f * mean * mean) * (1.f / 1023.f);
    var = fmaxf(var, 0.f);
    const float inv = 1.f / (sqrtf(var) + 1e-6f);
    bf16x4 pb;
#pragma unroll
    for (int j = 0; j < 4; ++j) {
      const int col = tid * 4 + j;
      float y = g[col] * (a4[j] - mean) * inv + bta[col];
      const float ang =
          (float)(row & 511) * exp2f((float)col * -0.025952563241307518f);
      y += (col & 1) ? cosf(ang) : sinf(ang);
      pb[j] = (short)f2b(y);
    }
    *(bf16x4*)(xb + base) = pb;
  } else {
    const int gid = (blockIdx.x - 4096) * 256 + threadIdx.x;
    if (gid < 1572864) {
      const int chunk = gid >> 18;
      const int off = (gid & 262143) * 4;
      const float* s;
      unsigned short* d;
      switch (chunk) {
        case 0: s = Wq; d = wqkv; break;
        case 1: s = Wk; d = wqkv + 1048576; break;
        case 2: s = Wv; d = wqkv + 2097152; break;
        case 3: s = Wo; d = wo; break;
        case 4: s = W1; d = w1; break;
        default: s = W2; d = w2; break;
      }
      const float4 v = *(const float4*)(s + off);
      bf16x4 o;
      o[0] = (short)f2b(v.x); o[1] = (short)f2b(v.y);
      o[2] = (short)f2b(v.z); o[3] = (short)f2b(v.w);
      *(bf16x4*)(d + off) = o;
    } else {
      const int idx = (gid - 1572864) * 4;
      if (idx < 3072) {
        const float* bs = idx < 1024 ? bq : (idx < 2048 ? bk - 1024 : bv - 2048);
        *(float4*)(bqkv + idx) = *(const float4*)(bs + idx);
      }
    }
  }
}

extern "C" void kernel_launch(void* const* d_in, const int* in_sizes, int n_in,
                              void* d_out, int out_size, void* d_ws, size_t ws_size,
                              hipStream_t stream) {
  (void)in_sizes; (void)n_in; (void)out_size; (void)ws_size;
  const float* features = (const float*)d_in[0];
  const int* mask = (const int*)d_in[1];
  const float* ln_in_g = (const float*)d_in[2];
  const float* ln_in_b = (const float*)d_in[3];
  const size_t DD = 1024 * 1024;
  // layer index 1 (the only live layer)
  const float* Wq = (const float*)d_in[4] + DD;
  const float* bq = (const float*)d_in[5] + 1024;
  const float* Wk = (const float*)d_in[6] + DD;
  const float* bk = (const float*)d_in[7] + 1024;
  const float* Wv = (const float*)d_in[8] + DD;
  const float* bv = (const float*)d_in[9] + 1024;
  const float* Wo = (const float*)d_in[10] + DD;
  const float* bo = (const float*)d_in[11] + 1024;
  const float* l1g = (const float*)d_in[12] + 1024;
  const float* l1b = (const float*)d_in[13] + 1024;
  const float* W1 = (const float*)d_in[14] + DD;
  const float* b1 = (const float*)d_in[15] + 1024;
  const float* W2 = (const float*)d_in[16] + DD;
  const float* b2 = (const float*)d_in[17] + 1024;
  const float* l2g = (const float*)d_in[18] + 1024;
  const float* l2b = (const float*)d_in[19] + 1024;

  char* base = (char*)d_ws;
  unsigned short* qkv = (unsigned short*)(base);              // 24 MB [4096][3072]
  unsigned short* xb = (unsigned short*)(base + 25165824);    // 8 MB: x bf16, then h
  unsigned short* ctxb = (unsigned short*)(base + 33554432);  // 8 MB: ctx, then s
  unsigned short* abuf = (unsigned short*)(base + 41943040);  // 8 MB: attn_out, then f
  unsigned short* wqkv = (unsigned short*)(base + 50331648);  // 6 MB [3072][1024]
  unsigned short* wo = (unsigned short*)(base + 56623104);    // 2 MB
  unsigned short* w1 = (unsigned short*)(base + 58720256);    // 2 MB
  unsigned short* w2 = (unsigned short*)(base + 60817408);    // 2 MB
  float* bqkv = (float*)(base + 62914560);                    // 12 KB

  hipFuncSetAttribute((const void*)gemm_t<128, 1>,
                      hipFuncAttributeMaxDynamicSharedMemorySize, 98304);
  hipFuncSetAttribute((const void*)gemm_t<64, 2>,
                      hipFuncAttributeMaxDynamicSharedMemorySize, 73728);
  hipFuncSetAttribute((const void*)gemm_t<64, 3>,
                      hipFuncAttributeMaxDynamicSharedMemorySize, 73728);
  hipFuncSetAttribute((const void*)attn_kernel,
                      hipFuncAttributeMaxDynamicSharedMemorySize, 67584);

  // fused: x = LN(features)+PE -> bf16  AND  weight converts + bias pack
  prep_ln<<<4096 + 6147, 256, 0, stream>>>(
      features, ln_in_g, ln_in_b, xb, Wq, Wk, Wv, Wo, W1, W2, bq, bk, bv,
      wqkv, wo, w1, w2, bqkv);
  // fused QKV projection (Q pre-scaled by 1/8): 32m x 24n = 768 blocks
  gemm_t<128, 1><<<768, 256, 98304, stream>>>(xb, wqkv, bqkv, qkv, 3072, 1024, 12);
  // attention
  attn_kernel<<<1024, 256, 67584, stream>>>(qkv, mask, ctxb);
  // attn_out = ctx @ Wo^T + bo -> bf16 : 32m x 16n = 512 blocks
  gemm_t<64, 3><<<512, 256, 73728, stream>>>(ctxb, wo, bo, abuf, 1024, 1024, 8);
  // s = LN(attn_out + x) -> bf16 (overwrites ctx)
  ln_k<1><<<4096, 256, 0, stream>>>(abuf, xb, l1g, l1b, ctxb);
  // h = gelu(s @ W1^T + b1) -> bf16 (overwrites x)
  gemm_t<64, 2><<<512, 256, 73728, stream>>>(ctxb, w1, b1, xb, 1024, 1024, 8);
  // f = h @ W2^T + b2 -> bf16 (overwrites attn_out)
  gemm_t<64, 3><<<512, 256, 73728, stream>>>(xb, w2, b2, abuf, 1024, 1024, 8);
  // out = LN(f + s) -> f32
  ln_k<2><<<4096, 256, 0, stream>>>(abuf, ctxb, l2g, l2b, (float*)d_out);
}

// Round 16
// 152.636 us; speedup vs baseline: 1.1115x; 1.0019x over previous
//
#include <hip/hip_runtime.h>
#include <cstdint>
#include <cstddef>

// Only layer i=1 is live (reference loop re-reads x, so layer 0 is dead code).
// B=8, S=512, D=1024, H=16, DH=64. All GEMMs are M=4096, K=1024.
// All intermediates bf16; only final LN writes f32.
// Config = r15 (e2e-best 152.9) + head-major QKV layout:
//   qkv[tensor][head][batch][s][64] (slab 32768 elems per (t,h,b)) so the
//   attention kernel's K/V/Q accesses are contiguous per (h,b) instead of
//   64B-per-6KB gathers. GEMM epilogue write coalescing unchanged.

typedef __attribute__((ext_vector_type(8))) short bf16x8;
typedef __attribute__((ext_vector_type(4))) short bf16x4;
typedef __attribute__((ext_vector_type(4))) float f32x4;

#define MFMA16(a, b, c) __builtin_amdgcn_mfma_f32_16x16x32_bf16((a), (b), (c), 0, 0, 0)

__device__ __forceinline__ unsigned short f2b(float f) {
  union { float f; unsigned int u; } x; x.f = f;
  unsigned int r = x.u + 0x7fffu + ((x.u >> 16) & 1u);
  return (unsigned short)(r >> 16);
}

__device__ __forceinline__ float b2f(unsigned short u) {
  union { unsigned int i; float f; } x;
  x.i = ((unsigned int)u) << 16;
  return x.f;
}

__device__ __forceinline__ void gl_lds16(const void* g, void* l) {
  __builtin_amdgcn_global_load_lds(
      (const __attribute__((address_space(1))) void*)g,
      (__attribute__((address_space(3))) void*)l, 16, 0, 0);
}

// ---------------------------------------------------------------------------
// GEMM (r9/r15 structure verbatim): BM=128, BK=64, BN templated. 3-deep
// pipelined staging for BOTH A and B, COUNTED vmcnt, raw s_barrier per K-step,
// vmcnt(0) only at tail. Pre-swizzled global source (conflict-free).
// EPI: 1 = +bias, Q scaled 1/8, HEAD-MAJOR scatter; 2 = GELU; 3 = +bias.
// 1D grid, bijective XCD mapping: xcd=bid&7 owns an 8m x nnHalf region.
// ---------------------------------------------------------------------------
template <int BN, int EPI>
__global__ __launch_bounds__(256) void gemm_t(
    const unsigned short* __restrict__ A, const unsigned short* __restrict__ B,
    const float* __restrict__ bias, unsigned short* __restrict__ outB, int N,
    int K, int nnHalf) {
  extern __shared__ char smem[];
  char* la = smem;              // 3 x [128 rows][128 B]
  char* lb = smem + 3 * 16384;  // 3 x [BN rows][128 B]
  constexpr int NR = BN / 32;
  const int tid = threadIdx.x;
  const int l = tid & 63, w = tid >> 6;
  const int l15 = l & 15, l4 = l >> 4;
  const int xcd = blockIdx.x & 7, r = blockIdx.x >> 3;
  const int m0 = ((xcd >> 1) * 8 + (r & 7)) * 128;
  const int n0 = ((xcd & 1) * nnHalf + (r >> 3)) * BN;
  const int wr = (w >> 1) * 64, wc = (w & 1) * (BN / 2);
  const int NT = K >> 6;  // K-steps of 64

#define STAGE(buf, t)                                                         \
  {                                                                           \
    const int k0_ = (t) * 64;                                                 \
    _Pragma("unroll") for (int i = 0; i < 4; ++i) {                           \
      const int c = i * 256 + tid;                                            \
      const int row = c >> 3;                                                 \
      const int gch = (c & 7) ^ (row & 7);                                    \
      gl_lds16(A + (size_t)(m0 + row) * K + k0_ + gch * 8,                    \
               la + (buf) * 16384 + (i * 256 + w * 64) * 16);                 \
    }                                                                         \
    _Pragma("unroll") for (int i = 0; i < BN / 32; ++i) {                     \
      const int c = i * 256 + tid;                                            \
      const int row = c >> 3;                                                 \
      const int gch = (c & 7) ^ (row & 7);                                    \
      gl_lds16(B + (size_t)(n0 + row) * K + k0_ + gch * 8,                    \
               lb + (buf) * (BN * 128) + (i * 256 + w * 64) * 16);            \
    }                                                                         \
  }
#define WAIT_L()                                                   \
  {                                                                \
    if constexpr (BN == 128) {                                     \
      asm volatile("s_waitcnt vmcnt(8)" ::: "memory");             \
    } else {                                                       \
      asm volatile("s_waitcnt vmcnt(6)" ::: "memory");             \
    }                                                              \
  }

  f32x4 acc[4][NR] = {};
  const int sw = l15 & 7;

  STAGE(0, 0);
  STAGE(1, 1);
  WAIT_L();  // tile 0 landed (tile 1 still in flight)
  __builtin_amdgcn_sched_barrier(0);
  __builtin_amdgcn_s_barrier();
  __builtin_amdgcn_sched_barrier(0);

  for (int t = 0; t < NT; ++t) {
    if (t + 2 < NT) {
      STAGE((t + 2) % 3, t + 2);
    }
    __builtin_amdgcn_sched_barrier(0);
    const char* abuf = la + (t % 3) * 16384;
    const char* bbuf = lb + (t % 3) * (BN * 128);
#pragma unroll
    for (int kk = 0; kk < 2; ++kk) {
      const unsigned int ch = (unsigned int)(((kk * 4 + l4) ^ sw) << 4);
      bf16x8 af[4], bfr[NR];
#pragma unroll
      for (int m = 0; m < 4; ++m)
        af[m] = *(const bf16x8*)(abuf + (wr + m * 16 + l15) * 128 + ch);
#pragma unroll
      for (int n = 0; n < NR; ++n)
        bfr[n] = *(const bf16x8*)(bbuf + (wc + n * 16 + l15) * 128 + ch);
#pragma unroll
      for (int m = 0; m < 4; ++m) {
#pragma unroll
        for (int n = 0; n < NR; ++n) {
          acc[m][n] = MFMA16(af[m], bfr[n], acc[m][n]);
        }
      }
    }
    if (t < NT - 1) {
      if (t + 2 < NT) {
        WAIT_L();  // tile t+1 landed; tile t+2 still in flight
      } else {
        asm volatile("s_waitcnt vmcnt(0)" ::: "memory");  // tail drain
      }
      __builtin_amdgcn_sched_barrier(0);
      __builtin_amdgcn_s_barrier();
      __builtin_amdgcn_sched_barrier(0);
    }
  }
#undef STAGE
#undef WAIT_L

#pragma unroll
  for (int m = 0; m < 4; ++m) {
#pragma unroll
    for (int n = 0; n < NR; ++n) {
      const int col = n0 + wc + n * 16 + l15;
      const float bb = bias[col];
#pragma unroll
      for (int e = 0; e < 4; ++e) {
        const int row = m0 + wr + m * 16 + l4 * 4 + e;
        float v = acc[m][n][e] + bb;
        if (EPI == 1) {
          // head-major scatter: [tensor][head][batch][s][64]
          const int tsr = col >> 10;
          const int hh = (col >> 6) & 15;
          const int dh = col & 63;
          if (tsr == 0) v *= 0.125f;  // fold 1/sqrt(DH) into Q
          const size_t off =
              (((size_t)((tsr * 16 + hh) * 8 + (row >> 9))) << 15) +
              ((size_t)(row & 511) << 6) + dh;
          outB[off] = f2b(v);
        } else {
          if (EPI == 2) {
            v = 0.5f * v * (1.f + erff(v * 0.70710678118654752f));
          }
          outB[(size_t)row * N + col] = f2b(v);
        }
      }
    }
  }
}

// ---------------------------------------------------------------------------
// Attention v7: r15 structure with head-major QKV input. Per-(h,b) slab is
// contiguous (32768 elems): K staged via 4x global_load_lds/thread from a
// CONTIGUOUS 16KB tile with pre-swizzled source (same lds[row][ch] =
// global[row][ch^(row&7)] relation as before -> reads untouched). V reg-staged
// transpose (row stride 128B now). LDS maskadd kept (r14 showed direct-global
// mask costs ~6us). Double-buffered, XCD-local b=bid&7, T14 split.
// ---------------------------------------------------------------------------
__global__ __launch_bounds__(256, 2) void attn_kernel(
    const unsigned short* __restrict__ qkv, const int* __restrict__ mask,
    unsigned short* __restrict__ ctx) {
  extern __shared__ char smem[];
  float* maskadd = (float*)(smem + 65536);  // [512]
  const int bid = blockIdx.x;
  const int b = bid & 7, h = (bid >> 3) & 15, qt = bid >> 7;
  const int tid = threadIdx.x, l = tid & 63, w = tid >> 6;
  const int l15 = l & 15, l4 = l >> 4;

  for (int s = tid; s < 512; s += 256)
    maskadd[s] = mask[b * 512 + s] ? 0.f : -1e18f;

  const unsigned short* Qb = qkv + (((size_t)(h * 8 + b)) << 15);
  const unsigned short* Kb = qkv + (((size_t)((16 + h) * 8 + b)) << 15);
  const unsigned short* Vb = qkv + (((size_t)((32 + h) * 8 + b)) << 15);

  // K staging: contiguous 16KB tile, pre-swizzled source, linear LDS dest.
#define STAGE_K(dstbuf, sn_)                                          \
  {                                                                   \
    _Pragma("unroll") for (int i = 0; i < 4; ++i) {                   \
      const int c = i * 256 + tid;                                    \
      const int row = c >> 3;                                         \
      const int gch = (c & 7) ^ (row & 7);                            \
      gl_lds16(Kb + (size_t)((sn_) + row) * 64 + gch * 8,             \
               (dstbuf) + c * 16);                                    \
    }                                                                 \
  }

  const int vs0 = 2 * l, vd0 = w * 16;
  bf16x8 vreg[4];
#define VLOAD(sn_)                                                          \
  {                                                                         \
    vreg[0] = *(const bf16x8*)(Vb + (size_t)((sn_) + vs0) * 64 + vd0);      \
    vreg[1] = *(const bf16x8*)(Vb + (size_t)((sn_) + vs0) * 64 + vd0 + 8);  \
    vreg[2] = *(const bf16x8*)(Vb + (size_t)((sn_) + vs0 + 1) * 64 + vd0);  \
    vreg[3] = *(const bf16x8*)(Vb + (size_t)((sn_) + vs0 + 1) * 64 + vd0 + 8); \
  }
#define VWRITE(dst)                                                          \
  {                                                                          \
    _Pragma("unroll") for (int j = 0; j < 16; ++j) {                         \
      const unsigned short lo_ =                                             \
          (unsigned short)((j < 8) ? vreg[0][j] : vreg[1][j - 8]);           \
      const unsigned short hi_ =                                             \
          (unsigned short)((j < 8) ? vreg[2][j] : vreg[3][j - 8]);           \
      *(unsigned int*)((dst) +                                               \
                       (((vd0 + j) * 256 + vs0 * 2) ^ ((j & 7) << 4))) =     \
          (unsigned int)lo_ | ((unsigned int)hi_ << 16);                     \
    }                                                                        \
  }

  // Q fragments (B operand: col=q=l15, k=dh)
  const int q0 = qt * 64 + w * 16;
  const unsigned short* qb = Qb + (size_t)(q0 + l15) * 64 + l4 * 8;
  const bf16x8 qf0 = *(const bf16x8*)(qb);
  const bf16x8 qf1 = *(const bf16x8*)(qb + 32);

  // prologue: tile 0
  STAGE_K(smem, 0);
  VLOAD(0);
  VWRITE(smem + 32768);
  __syncthreads();

  const int hi4 = l4 >> 1, gl = l4 & 1, g2 = l4 & 2;
  f32x4 acc[4] = {};
  float run_m = -1e30f, run_s = 0.f;

#pragma unroll
  for (int t = 0; t < 4; ++t) {
    char* kcur = smem + (t & 1) * 16384;
    char* vcur = smem + 32768 + (t & 1) * 16384;
    char* knxt = smem + ((t + 1) & 1) * 16384;
    char* vnxt = smem + 32768 + ((t + 1) & 1) * 16384;
    if (t < 3) {
      const int sn = (t + 1) * 128;
      STAGE_K(knxt, sn);  // async into the buffer read last iteration
      VLOAD(sn);          // regs; written to LDS after PV
      __builtin_amdgcn_sched_barrier(0);
    }
    f32x4 sc[8];
    __builtin_amdgcn_s_setprio(1);
#pragma unroll
    for (int kk = 0; kk < 8; ++kk) {
      const unsigned int lin = (unsigned int)((kk * 16 + l15) * 128 + l4 * 16);
      const unsigned int swz = (unsigned int)((l15 & 7) << 4);
      const bf16x8 af0 = *(const bf16x8*)(kcur + (lin ^ swz));
      const bf16x8 af1 = *(const bf16x8*)(kcur + ((lin + 64) ^ swz));
      f32x4 c = {0.f, 0.f, 0.f, 0.f};
      c = MFMA16(af0, qf0, c);
      c = MFMA16(af1, qf1, c);
      sc[kk] = c;
    }
    __builtin_amdgcn_s_setprio(0);
    float tmx = -1e30f;
#pragma unroll
    for (int kk = 0; kk < 8; ++kk) {
#pragma unroll
      for (int e = 0; e < 4; ++e) {
        const float v = sc[kk][e] + maskadd[t * 128 + kk * 16 + l4 * 4 + e];
        sc[kk][e] = v;
        tmx = fmaxf(tmx, v);
      }
    }
    tmx = fmaxf(tmx, __shfl_xor(tmx, 16));
    tmx = fmaxf(tmx, __shfl_xor(tmx, 32));
    const float nm = (t == 0) ? tmx : fmaxf(run_m, tmx);
    float tsum = 0.f;
    unsigned int pk[8][2];
#pragma unroll
    for (int kk = 0; kk < 8; ++kk) {
      const float p0 = __expf(sc[kk][0] - nm);
      const float p1 = __expf(sc[kk][1] - nm);
      const float p2 = __expf(sc[kk][2] - nm);
      const float p3 = __expf(sc[kk][3] - nm);
      tsum += (p0 + p1) + (p2 + p3);
      asm("v_cvt_pk_bf16_f32 %0, %1, %2" : "=v"(pk[kk][0]) : "v"(p0), "v"(p1));
      asm("v_cvt_pk_bf16_f32 %0, %1, %2" : "=v"(pk[kk][1]) : "v"(p2), "v"(p3));
    }
    tsum += __shfl_xor(tsum, 16);
    tsum += __shfl_xor(tsum, 32);
    if (t == 0) {
      run_s = tsum;
    } else {
      const float scale = __expf(run_m - nm);
      run_s = run_s * scale + tsum;
      float s4[4];
#pragma unroll
      for (int e = 0; e < 4; ++e) s4[e] = __shfl(scale, l4 * 4 + e);
#pragma unroll
      for (int nt = 0; nt < 4; ++nt) {
#pragma unroll
        for (int e = 0; e < 4; ++e) acc[nt][e] *= s4[e];
      }
    }
    run_m = nm;
#pragma unroll
    for (int k2 = 0; k2 < 4; ++k2) {
      const unsigned int own0 = hi4 ? pk[2 * k2 + 1][0] : pk[2 * k2][0];
      const unsigned int own1 = hi4 ? pk[2 * k2 + 1][1] : pk[2 * k2][1];
      const unsigned int oth0 = hi4 ? pk[2 * k2][0] : pk[2 * k2 + 1][0];
      const unsigned int oth1 = hi4 ? pk[2 * k2][1] : pk[2 * k2 + 1][1];
      const unsigned int s16_0 = (unsigned int)__shfl_xor((int)own0, 16);
      const unsigned int s16_1 = (unsigned int)__shfl_xor((int)own1, 16);
      const unsigned int s32_0 = (unsigned int)__shfl_xor((int)oth0, 32);
      const unsigned int s32_1 = (unsigned int)__shfl_xor((int)oth1, 32);
      const unsigned int s48_0 = (unsigned int)__shfl_xor((int)oth0, 48);
      const unsigned int s48_1 = (unsigned int)__shfl_xor((int)oth1, 48);
      union { unsigned int u[4]; bf16x8 v; } pa;
      pa.u[0] = g2 ? (gl ? s16_0 : s32_0) : (gl ? s48_0 : own0);
      pa.u[1] = g2 ? (gl ? s16_1 : s32_1) : (gl ? s48_1 : own1);
      pa.u[2] = g2 ? (gl ? own0 : s48_0) : (gl ? s32_0 : s16_0);
      pa.u[3] = g2 ? (gl ? own1 : s48_1) : (gl ? s32_1 : s16_1);
      __builtin_amdgcn_s_setprio(1);
#pragma unroll
      for (int nt = 0; nt < 4; ++nt) {
        const int d = nt * 16 + l15;
        const unsigned int vb =
            (unsigned int)((d * 256 + k2 * 64 + l4 * 16) ^ ((l15 & 7) << 4));
        const bf16x8 vbf = *(const bf16x8*)(vcur + vb);
        acc[nt] = MFMA16(pa.v, vbf, acc[nt]);
      }
      __builtin_amdgcn_s_setprio(0);
    }
    if (t < 3) {
      VWRITE(vnxt);
      __syncthreads();  // drains STAGE_K vmcnt + orders VWRITE
    }
  }
#undef STAGE_K
#undef VLOAD
#undef VWRITE

  const float inv = 1.f / run_s;
  float invq[4];
#pragma unroll
  for (int e = 0; e < 4; ++e) invq[e] = __shfl(inv, l4 * 4 + e);
#pragma unroll
  for (int nt = 0; nt < 4; ++nt) {
#pragma unroll
    for (int e = 0; e < 4; ++e) {
      const size_t row = (size_t)b * 512 + q0 + l4 * 4 + e;
      ctx[row * 1024 + h * 64 + nt * 16 + l15] = f2b(acc[nt][e] * invq[e]);
    }
  }
}

// ---------------------------------------------------------------------------
// Custom LayerNorm (unbiased std, eps added to std). One block per row.
// MODE 1: A bf16, R bf16, out bf16.  MODE 2: A bf16, R bf16, out f32.
// ---------------------------------------------------------------------------
template <int MODE>
__global__ __launch_bounds__(256) void ln_k(
    const void* __restrict__ Ap, const void* __restrict__ Rp,
    const float* __restrict__ g, const float* __restrict__ bta,
    void* __restrict__ outp) {
  __shared__ float red[8];
  const int row = blockIdx.x, tid = threadIdx.x;
  const size_t base = (size_t)row * 1024 + tid * 4;
  float a4[4];
  {
    const bf16x4 a = *(const bf16x4*)((const unsigned short*)Ap + base);
    const bf16x4 rr = *(const bf16x4*)((const unsigned short*)Rp + base);
#pragma unroll
    for (int j = 0; j < 4; ++j)
      a4[j] = b2f((unsigned short)a[j]) + b2f((unsigned short)rr[j]);
  }
  float s = a4[0] + a4[1] + a4[2] + a4[3];
  float q = a4[0] * a4[0] + a4[1] * a4[1] + a4[2] * a4[2] + a4[3] * a4[3];
#pragma unroll
  for (int o = 32; o; o >>= 1) {
    s += __shfl_xor(s, o);
    q += __shfl_xor(q, o);
  }
  if ((tid & 63) == 0) {
    red[(tid >> 6) * 2] = s;
    red[(tid >> 6) * 2 + 1] = q;
  }
  __syncthreads();
  const float S = red[0] + red[2] + red[4] + red[6];
  const float Qs = red[1] + red[3] + red[5] + red[7];
  const float mean = S * (1.f / 1024.f);
  float var = (Qs - 1024.f * mean * mean) * (1.f / 1023.f);
  var = fmaxf(var, 0.f);
  const float inv = 1.f / (sqrtf(var) + 1e-6f);
  if (MODE == 2) {
    float4 o4;
    o4.x = g[tid * 4 + 0] * (a4[0] - mean) * inv + bta[tid * 4 + 0];
    o4.y = g[tid * 4 + 1] * (a4[1] - mean) * inv + bta[tid * 4 + 1];
    o4.z = g[tid * 4 + 2] * (a4[2] - mean) * inv + bta[tid * 4 + 2];
    o4.w = g[tid * 4 + 3] * (a4[3] - mean) * inv + bta[tid * 4 + 3];
    *(float4*)((float*)outp + base) = o4;
  } else {
    bf16x4 pb;
#pragma unroll
    for (int j = 0; j < 4; ++j) {
      const int col = tid * 4 + j;
      pb[j] = (short)f2b(g[col] * (a4[j] - mean) * inv + bta[col]);
    }
    *(bf16x4*)((unsigned short*)outp + base) = pb;
  }
}

// ---------------------------------------------------------------------------
// Fused (r13/r15-verified): input LN (+PE) for blocks < 4096; weight
// f32->bf16 convert + QKV bias pack for the rest. One dispatch.
// ---------------------------------------------------------------------------
__global__ __launch_bounds__(256) void prep_ln(
    const float* __restrict__ features, const float* __restrict__ g,
    const float* __restrict__ bta, unsigned short* __restrict__ xb,
    const float* __restrict__ Wq, const float* __restrict__ Wk,
    const float* __restrict__ Wv, const float* __restrict__ Wo,
    const float* __restrict__ W1, const float* __restrict__ W2,
    const float* __restrict__ bq, const float* __restrict__ bk,
    const float* __restrict__ bv, unsigned short* __restrict__ wqkv,
    unsigned short* __restrict__ wo, unsigned short* __restrict__ w1,
    unsigned short* __restrict__ w2, float* __restrict__ bqkv) {
  if (blockIdx.x < 4096) {
    __shared__ float red[8];
    const int row = blockIdx.x, tid = threadIdx.x;
    const size_t base = (size_t)row * 1024 + tid * 4;
    const float4 a = *(const float4*)(features + base);
    float a4[4] = {a.x, a.y, a.z, a.w};
    float s = a4[0] + a4[1] + a4[2] + a4[3];
    float q = a4[0] * a4[0] + a4[1] * a4[1] + a4[2] * a4[2] + a4[3] * a4[3];
#pragma unroll
    for (int o = 32; o; o >>= 1) {
      s += __shfl_xor(s, o);
      q += __shfl_xor(q, o);
    }
    if ((tid & 63) == 0) {
      red[(tid >> 6) * 2] = s;
      red[(tid >> 6) * 2 + 1] = q;
    }
    __syncthreads();
    const float S = red[0] + red[2] + red[4] + red[6];
    const float Qs = red[1] + red[3] + red[5] + red[7];
    const float mean = S * (1.f / 1024.f);
    float var = (Qs - 1024.f * mean * mean) * (1.f / 1023.f);
    var = fmaxf(var, 0.f);
    const float inv = 1.f / (sqrtf(var) + 1e-6f);
    bf16x4 pb;
#pragma unroll
    for (int j = 0; j < 4; ++j) {
      const int col = tid * 4 + j;
      float y = g[col] * (a4[j] - mean) * inv + bta[col];
      const float ang =
          (float)(row & 511) * exp2f((float)col * -0.025952563241307518f);
      y += (col & 1) ? cosf(ang) : sinf(ang);
      pb[j] = (short)f2b(y);
    }
    *(bf16x4*)(xb + base) = pb;
  } else {
    const int gid = (blockIdx.x - 4096) * 256 + threadIdx.x;
    if (gid < 1572864) {
      const int chunk = gid >> 18;
      const int off = (gid & 262143) * 4;
      const float* s;
      unsigned short* d;
      switch (chunk) {
        case 0: s = Wq; d = wqkv; break;
        case 1: s = Wk; d = wqkv + 1048576; break;
        case 2: s = Wv; d = wqkv + 2097152; break;
        case 3: s = Wo; d = wo; break;
        case 4: s = W1; d = w1; break;
        default: s = W2; d = w2; break;
      }
      const float4 v = *(const float4*)(s + off);
      bf16x4 o;
      o[0] = (short)f2b(v.x); o[1] = (short)f2b(v.y);
      o[2] = (short)f2b(v.z); o[3] = (short)f2b(v.w);
      *(bf16x4*)(d + off) = o;
    } else {
      const int idx = (gid - 1572864) * 4;
      if (idx < 3072) {
        const float* bs = idx < 1024 ? bq : (idx < 2048 ? bk - 1024 : bv - 2048);
        *(float4*)(bqkv + idx) = *(const float4*)(bs + idx);
      }
    }
  }
}

extern "C" void kernel_launch(void* const* d_in, const int* in_sizes, int n_in,
                              void* d_out, int out_size, void* d_ws, size_t ws_size,
                              hipStream_t stream) {
  (void)in_sizes; (void)n_in; (void)out_size; (void)ws_size;
  const float* features = (const float*)d_in[0];
  const int* mask = (const int*)d_in[1];
  const float* ln_in_g = (const float*)d_in[2];
  const float* ln_in_b = (const float*)d_in[3];
  const size_t DD = 1024 * 1024;
  // layer index 1 (the only live layer)
  const float* Wq = (const float*)d_in[4] + DD;
  const float* bq = (const float*)d_in[5] + 1024;
  const float* Wk = (const float*)d_in[6] + DD;
  const float* bk = (const float*)d_in[7] + 1024;
  const float* Wv = (const float*)d_in[8] + DD;
  const float* bv = (const float*)d_in[9] + 1024;
  const float* Wo = (const float*)d_in[10] + DD;
  const float* bo = (const float*)d_in[11] + 1024;
  const float* l1g = (const float*)d_in[12] + 1024;
  const float* l1b = (const float*)d_in[13] + 1024;
  const float* W1 = (const float*)d_in[14] + DD;
  const float* b1 = (const float*)d_in[15] + 1024;
  const float* W2 = (const float*)d_in[16] + DD;
  const float* b2 = (const float*)d_in[17] + 1024;
  const float* l2g = (const float*)d_in[18] + 1024;
  const float* l2b = (const float*)d_in[19] + 1024;

  char* base = (char*)d_ws;
  unsigned short* qkv = (unsigned short*)(base);              // 24 MB head-major
  unsigned short* xb = (unsigned short*)(base + 25165824);    // 8 MB: x bf16, then h
  unsigned short* ctxb = (unsigned short*)(base + 33554432);  // 8 MB: ctx, then s
  unsigned short* abuf = (unsigned short*)(base + 41943040);  // 8 MB: attn_out, then f
  unsigned short* wqkv = (unsigned short*)(base + 50331648);  // 6 MB [3072][1024]
  unsigned short* wo = (unsigned short*)(base + 56623104);    // 2 MB
  unsigned short* w1 = (unsigned short*)(base + 58720256);    // 2 MB
  unsigned short* w2 = (unsigned short*)(base + 60817408);    // 2 MB
  float* bqkv = (float*)(base + 62914560);                    // 12 KB

  hipFuncSetAttribute((const void*)gemm_t<128, 1>,
                      hipFuncAttributeMaxDynamicSharedMemorySize, 98304);
  hipFuncSetAttribute((const void*)gemm_t<64, 2>,
                      hipFuncAttributeMaxDynamicSharedMemorySize, 73728);
  hipFuncSetAttribute((const void*)gemm_t<64, 3>,
                      hipFuncAttributeMaxDynamicSharedMemorySize, 73728);
  hipFuncSetAttribute((const void*)attn_kernel,
                      hipFuncAttributeMaxDynamicSharedMemorySize, 67584);

  // fused: x = LN(features)+PE -> bf16  AND  weight converts + bias pack
  prep_ln<<<4096 + 6147, 256, 0, stream>>>(
      features, ln_in_g, ln_in_b, xb, Wq, Wk, Wv, Wo, W1, W2, bq, bk, bv,
      wqkv, wo, w1, w2, bqkv);
  // fused QKV projection -> head-major layout: 32m x 24n = 768 blocks
  gemm_t<128, 1><<<768, 256, 98304, stream>>>(xb, wqkv, bqkv, qkv, 3072, 1024, 12);
  // attention
  attn_kernel<<<1024, 256, 67584, stream>>>(qkv, mask, ctxb);
  // attn_out = ctx @ Wo^T + bo -> bf16 : 32m x 16n = 512 blocks
  gemm_t<64, 3><<<512, 256, 73728, stream>>>(ctxb, wo, bo, abuf, 1024, 1024, 8);
  // s = LN(attn_out + x) -> bf16 (overwrites ctx)
  ln_k<1><<<4096, 256, 0, stream>>>(abuf, xb, l1g, l1b, ctxb);
  // h = gelu(s @ W1^T + b1) -> bf16 (overwrites x)
  gemm_t<64, 2><<<512, 256, 73728, stream>>>(ctxb, w1, b1, xb, 1024, 1024, 8);
  // f = h @ W2^T + b2 -> bf16 (overwrites attn_out)
  gemm_t<64, 3><<<512, 256, 73728, stream>>>(xb, w2, b2, abuf, 1024, 1024, 8);
  // out = LN(f + s) -> f32
  ln_k<2><<<4096, 256, 0, stream>>>(abuf, ctxb, l2g, l2b, (float*)d_out);
}

// Round 17
// 152.213 us; speedup vs baseline: 1.1146x; 1.0028x over previous
//
#include <hip/hip_runtime.h>
#include <cstdint>
#include <cstddef>

// Only layer i=1 is live (reference loop re-reads x, so layer 0 is dead code).
// B=8, S=512, D=1024, H=16, DH=64. All GEMMs are M=4096, K=1024.
// All intermediates bf16; only final LN writes f32.
// Config = r16 (e2e-best 152.6) + T5 s_setprio around GEMM MFMA clusters.

typedef __attribute__((ext_vector_type(8))) short bf16x8;
typedef __attribute__((ext_vector_type(4))) short bf16x4;
typedef __attribute__((ext_vector_type(4))) float f32x4;

#define MFMA16(a, b, c) __builtin_amdgcn_mfma_f32_16x16x32_bf16((a), (b), (c), 0, 0, 0)

__device__ __forceinline__ unsigned short f2b(float f) {
  union { float f; unsigned int u; } x; x.f = f;
  unsigned int r = x.u + 0x7fffu + ((x.u >> 16) & 1u);
  return (unsigned short)(r >> 16);
}

__device__ __forceinline__ float b2f(unsigned short u) {
  union { unsigned int i; float f; } x;
  x.i = ((unsigned int)u) << 16;
  return x.f;
}

__device__ __forceinline__ void gl_lds16(const void* g, void* l) {
  __builtin_amdgcn_global_load_lds(
      (const __attribute__((address_space(1))) void*)g,
      (__attribute__((address_space(3))) void*)l, 16, 0, 0);
}

// ---------------------------------------------------------------------------
// GEMM (r9/r15 structure + T5): BM=128, BK=64, BN templated. 3-deep pipelined
// staging for BOTH A and B, COUNTED vmcnt, raw s_barrier per K-step, vmcnt(0)
// only at tail. Pre-swizzled global source (conflict-free). s_setprio(1)
// wraps the MFMA cluster (T5 — scheduler favors compute-phase waves).
// EPI: 1 = +bias, Q scaled 1/8, HEAD-MAJOR scatter; 2 = GELU; 3 = +bias.
// 1D grid, bijective XCD mapping: xcd=bid&7 owns an 8m x nnHalf region.
// ---------------------------------------------------------------------------
template <int BN, int EPI>
__global__ __launch_bounds__(256) void gemm_t(
    const unsigned short* __restrict__ A, const unsigned short* __restrict__ B,
    const float* __restrict__ bias, unsigned short* __restrict__ outB, int N,
    int K, int nnHalf) {
  extern __shared__ char smem[];
  char* la = smem;              // 3 x [128 rows][128 B]
  char* lb = smem + 3 * 16384;  // 3 x [BN rows][128 B]
  constexpr int NR = BN / 32;
  const int tid = threadIdx.x;
  const int l = tid & 63, w = tid >> 6;
  const int l15 = l & 15, l4 = l >> 4;
  const int xcd = blockIdx.x & 7, r = blockIdx.x >> 3;
  const int m0 = ((xcd >> 1) * 8 + (r & 7)) * 128;
  const int n0 = ((xcd & 1) * nnHalf + (r >> 3)) * BN;
  const int wr = (w >> 1) * 64, wc = (w & 1) * (BN / 2);
  const int NT = K >> 6;  // K-steps of 64

#define STAGE(buf, t)                                                         \
  {                                                                           \
    const int k0_ = (t) * 64;                                                 \
    _Pragma("unroll") for (int i = 0; i < 4; ++i) {                           \
      const int c = i * 256 + tid;                                            \
      const int row = c >> 3;                                                 \
      const int gch = (c & 7) ^ (row & 7);                                    \
      gl_lds16(A + (size_t)(m0 + row) * K + k0_ + gch * 8,                    \
               la + (buf) * 16384 + (i * 256 + w * 64) * 16);                 \
    }                                                                         \
    _Pragma("unroll") for (int i = 0; i < BN / 32; ++i) {                     \
      const int c = i * 256 + tid;                                            \
      const int row = c >> 3;                                                 \
      const int gch = (c & 7) ^ (row & 7);                                    \
      gl_lds16(B + (size_t)(n0 + row) * K + k0_ + gch * 8,                    \
               lb + (buf) * (BN * 128) + (i * 256 + w * 64) * 16);            \
    }                                                                         \
  }
#define WAIT_L()                                                   \
  {                                                                \
    if constexpr (BN == 128) {                                     \
      asm volatile("s_waitcnt vmcnt(8)" ::: "memory");             \
    } else {                                                       \
      asm volatile("s_waitcnt vmcnt(6)" ::: "memory");             \
    }                                                              \
  }

  f32x4 acc[4][NR] = {};
  const int sw = l15 & 7;

  STAGE(0, 0);
  STAGE(1, 1);
  WAIT_L();  // tile 0 landed (tile 1 still in flight)
  __builtin_amdgcn_sched_barrier(0);
  __builtin_amdgcn_s_barrier();
  __builtin_amdgcn_sched_barrier(0);

  for (int t = 0; t < NT; ++t) {
    if (t + 2 < NT) {
      STAGE((t + 2) % 3, t + 2);
    }
    __builtin_amdgcn_sched_barrier(0);
    const char* abuf = la + (t % 3) * 16384;
    const char* bbuf = lb + (t % 3) * (BN * 128);
    __builtin_amdgcn_s_setprio(1);  // T5: favor this wave through MFMA cluster
#pragma unroll
    for (int kk = 0; kk < 2; ++kk) {
      const unsigned int ch = (unsigned int)(((kk * 4 + l4) ^ sw) << 4);
      bf16x8 af[4], bfr[NR];
#pragma unroll
      for (int m = 0; m < 4; ++m)
        af[m] = *(const bf16x8*)(abuf + (wr + m * 16 + l15) * 128 + ch);
#pragma unroll
      for (int n = 0; n < NR; ++n)
        bfr[n] = *(const bf16x8*)(bbuf + (wc + n * 16 + l15) * 128 + ch);
#pragma unroll
      for (int m = 0; m < 4; ++m) {
#pragma unroll
        for (int n = 0; n < NR; ++n) {
          acc[m][n] = MFMA16(af[m], bfr[n], acc[m][n]);
        }
      }
    }
    __builtin_amdgcn_s_setprio(0);
    if (t < NT - 1) {
      if (t + 2 < NT) {
        WAIT_L();  // tile t+1 landed; tile t+2 still in flight
      } else {
        asm volatile("s_waitcnt vmcnt(0)" ::: "memory");  // tail drain
      }
      __builtin_amdgcn_sched_barrier(0);
      __builtin_amdgcn_s_barrier();
      __builtin_amdgcn_sched_barrier(0);
    }
  }
#undef STAGE
#undef WAIT_L

#pragma unroll
  for (int m = 0; m < 4; ++m) {
#pragma unroll
    for (int n = 0; n < NR; ++n) {
      const int col = n0 + wc + n * 16 + l15;
      const float bb = bias[col];
#pragma unroll
      for (int e = 0; e < 4; ++e) {
        const int row = m0 + wr + m * 16 + l4 * 4 + e;
        float v = acc[m][n][e] + bb;
        if (EPI == 1) {
          // head-major scatter: [tensor][head][batch][s][64]
          const int tsr = col >> 10;
          const int hh = (col >> 6) & 15;
          const int dh = col & 63;
          if (tsr == 0) v *= 0.125f;  // fold 1/sqrt(DH) into Q
          const size_t off =
              (((size_t)((tsr * 16 + hh) * 8 + (row >> 9))) << 15) +
              ((size_t)(row & 511) << 6) + dh;
          outB[off] = f2b(v);
        } else {
          if (EPI == 2) {
            v = 0.5f * v * (1.f + erff(v * 0.70710678118654752f));
          }
          outB[(size_t)row * N + col] = f2b(v);
        }
      }
    }
  }
}

// ---------------------------------------------------------------------------
// Attention v7 (r16 verbatim): head-major QKV input, contiguous K staging via
// global_load_lds (pre-swizzled source), V reg-staged transpose, LDS maskadd,
// double-buffered, XCD-local b=bid&7, T14 split.
// ---------------------------------------------------------------------------
__global__ __launch_bounds__(256, 2) void attn_kernel(
    const unsigned short* __restrict__ qkv, const int* __restrict__ mask,
    unsigned short* __restrict__ ctx) {
  extern __shared__ char smem[];
  float* maskadd = (float*)(smem + 65536);  // [512]
  const int bid = blockIdx.x;
  const int b = bid & 7, h = (bid >> 3) & 15, qt = bid >> 7;
  const int tid = threadIdx.x, l = tid & 63, w = tid >> 6;
  const int l15 = l & 15, l4 = l >> 4;

  for (int s = tid; s < 512; s += 256)
    maskadd[s] = mask[b * 512 + s] ? 0.f : -1e18f;

  const unsigned short* Qb = qkv + (((size_t)(h * 8 + b)) << 15);
  const unsigned short* Kb = qkv + (((size_t)((16 + h) * 8 + b)) << 15);
  const unsigned short* Vb = qkv + (((size_t)((32 + h) * 8 + b)) << 15);

#define STAGE_K(dstbuf, sn_)                                          \
  {                                                                   \
    _Pragma("unroll") for (int i = 0; i < 4; ++i) {                   \
      const int c = i * 256 + tid;                                    \
      const int row = c >> 3;                                         \
      const int gch = (c & 7) ^ (row & 7);                            \
      gl_lds16(Kb + (size_t)((sn_) + row) * 64 + gch * 8,             \
               (dstbuf) + c * 16);                                    \
    }                                                                 \
  }

  const int vs0 = 2 * l, vd0 = w * 16;
  bf16x8 vreg[4];
#define VLOAD(sn_)                                                          \
  {                                                                         \
    vreg[0] = *(const bf16x8*)(Vb + (size_t)((sn_) + vs0) * 64 + vd0);      \
    vreg[1] = *(const bf16x8*)(Vb + (size_t)((sn_) + vs0) * 64 + vd0 + 8);  \
    vreg[2] = *(const bf16x8*)(Vb + (size_t)((sn_) + vs0 + 1) * 64 + vd0);  \
    vreg[3] = *(const bf16x8*)(Vb + (size_t)((sn_) + vs0 + 1) * 64 + vd0 + 8); \
  }
#define VWRITE(dst)                                                          \
  {                                                                          \
    _Pragma("unroll") for (int j = 0; j < 16; ++j) {                         \
      const unsigned short lo_ =                                             \
          (unsigned short)((j < 8) ? vreg[0][j] : vreg[1][j - 8]);           \
      const unsigned short hi_ =                                             \
          (unsigned short)((j < 8) ? vreg[2][j] : vreg[3][j - 8]);           \
      *(unsigned int*)((dst) +                                               \
                       (((vd0 + j) * 256 + vs0 * 2) ^ ((j & 7) << 4))) =     \
          (unsigned int)lo_ | ((unsigned int)hi_ << 16);                     \
    }                                                                        \
  }

  const int q0 = qt * 64 + w * 16;
  const unsigned short* qb = Qb + (size_t)(q0 + l15) * 64 + l4 * 8;
  const bf16x8 qf0 = *(const bf16x8*)(qb);
  const bf16x8 qf1 = *(const bf16x8*)(qb + 32);

  STAGE_K(smem, 0);
  VLOAD(0);
  VWRITE(smem + 32768);
  __syncthreads();

  const int hi4 = l4 >> 1, gl = l4 & 1, g2 = l4 & 2;
  f32x4 acc[4] = {};
  float run_m = -1e30f, run_s = 0.f;

#pragma unroll
  for (int t = 0; t < 4; ++t) {
    char* kcur = smem + (t & 1) * 16384;
    char* vcur = smem + 32768 + (t & 1) * 16384;
    char* knxt = smem + ((t + 1) & 1) * 16384;
    char* vnxt = smem + 32768 + ((t + 1) & 1) * 16384;
    if (t < 3) {
      const int sn = (t + 1) * 128;
      STAGE_K(knxt, sn);
      VLOAD(sn);
      __builtin_amdgcn_sched_barrier(0);
    }
    f32x4 sc[8];
    __builtin_amdgcn_s_setprio(1);
#pragma unroll
    for (int kk = 0; kk < 8; ++kk) {
      const unsigned int lin = (unsigned int)((kk * 16 + l15) * 128 + l4 * 16);
      const unsigned int swz = (unsigned int)((l15 & 7) << 4);
      const bf16x8 af0 = *(const bf16x8*)(kcur + (lin ^ swz));
      const bf16x8 af1 = *(const bf16x8*)(kcur + ((lin + 64) ^ swz));
      f32x4 c = {0.f, 0.f, 0.f, 0.f};
      c = MFMA16(af0, qf0, c);
      c = MFMA16(af1, qf1, c);
      sc[kk] = c;
    }
    __builtin_amdgcn_s_setprio(0);
    float tmx = -1e30f;
#pragma unroll
    for (int kk = 0; kk < 8; ++kk) {
#pragma unroll
      for (int e = 0; e < 4; ++e) {
        const float v = sc[kk][e] + maskadd[t * 128 + kk * 16 + l4 * 4 + e];
        sc[kk][e] = v;
        tmx = fmaxf(tmx, v);
      }
    }
    tmx = fmaxf(tmx, __shfl_xor(tmx, 16));
    tmx = fmaxf(tmx, __shfl_xor(tmx, 32));
    const float nm = (t == 0) ? tmx : fmaxf(run_m, tmx);
    float tsum = 0.f;
    unsigned int pk[8][2];
#pragma unroll
    for (int kk = 0; kk < 8; ++kk) {
      const float p0 = __expf(sc[kk][0] - nm);
      const float p1 = __expf(sc[kk][1] - nm);
      const float p2 = __expf(sc[kk][2] - nm);
      const float p3 = __expf(sc[kk][3] - nm);
      tsum += (p0 + p1) + (p2 + p3);
      asm("v_cvt_pk_bf16_f32 %0, %1, %2" : "=v"(pk[kk][0]) : "v"(p0), "v"(p1));
      asm("v_cvt_pk_bf16_f32 %0, %1, %2" : "=v"(pk[kk][1]) : "v"(p2), "v"(p3));
    }
    tsum += __shfl_xor(tsum, 16);
    tsum += __shfl_xor(tsum, 32);
    if (t == 0) {
      run_s = tsum;
    } else {
      const float scale = __expf(run_m - nm);
      run_s = run_s * scale + tsum;
      float s4[4];
#pragma unroll
      for (int e = 0; e < 4; ++e) s4[e] = __shfl(scale, l4 * 4 + e);
#pragma unroll
      for (int nt = 0; nt < 4; ++nt) {
#pragma unroll
        for (int e = 0; e < 4; ++e) acc[nt][e] *= s4[e];
      }
    }
    run_m = nm;
#pragma unroll
    for (int k2 = 0; k2 < 4; ++k2) {
      const unsigned int own0 = hi4 ? pk[2 * k2 + 1][0] : pk[2 * k2][0];
      const unsigned int own1 = hi4 ? pk[2 * k2 + 1][1] : pk[2 * k2][1];
      const unsigned int oth0 = hi4 ? pk[2 * k2][0] : pk[2 * k2 + 1][0];
      const unsigned int oth1 = hi4 ? pk[2 * k2][1] : pk[2 * k2 + 1][1];
      const unsigned int s16_0 = (unsigned int)__shfl_xor((int)own0, 16);
      const unsigned int s16_1 = (unsigned int)__shfl_xor((int)own1, 16);
      const unsigned int s32_0 = (unsigned int)__shfl_xor((int)oth0, 32);
      const unsigned int s32_1 = (unsigned int)__shfl_xor((int)oth1, 32);
      const unsigned int s48_0 = (unsigned int)__shfl_xor((int)oth0, 48);
      const unsigned int s48_1 = (unsigned int)__shfl_xor((int)oth1, 48);
      union { unsigned int u[4]; bf16x8 v; } pa;
      pa.u[0] = g2 ? (gl ? s16_0 : s32_0) : (gl ? s48_0 : own0);
      pa.u[1] = g2 ? (gl ? s16_1 : s32_1) : (gl ? s48_1 : own1);
      pa.u[2] = g2 ? (gl ? own0 : s48_0) : (gl ? s32_0 : s16_0);
      pa.u[3] = g2 ? (gl ? own1 : s48_1) : (gl ? s32_1 : s16_1);
      __builtin_amdgcn_s_setprio(1);
#pragma unroll
      for (int nt = 0; nt < 4; ++nt) {
        const int d = nt * 16 + l15;
        const unsigned int vb =
            (unsigned int)((d * 256 + k2 * 64 + l4 * 16) ^ ((l15 & 7) << 4));
        const bf16x8 vbf = *(const bf16x8*)(vcur + vb);
        acc[nt] = MFMA16(pa.v, vbf, acc[nt]);
      }
      __builtin_amdgcn_s_setprio(0);
    }
    if (t < 3) {
      VWRITE(vnxt);
      __syncthreads();
    }
  }
#undef STAGE_K
#undef VLOAD
#undef VWRITE

  const float inv = 1.f / run_s;
  float invq[4];
#pragma unroll
  for (int e = 0; e < 4; ++e) invq[e] = __shfl(inv, l4 * 4 + e);
#pragma unroll
  for (int nt = 0; nt < 4; ++nt) {
#pragma unroll
    for (int e = 0; e < 4; ++e) {
      const size_t row = (size_t)b * 512 + q0 + l4 * 4 + e;
      ctx[row * 1024 + h * 64 + nt * 16 + l15] = f2b(acc[nt][e] * invq[e]);
    }
  }
}

// ---------------------------------------------------------------------------
// Custom LayerNorm (unbiased std, eps added to std). One block per row.
// MODE 1: A bf16, R bf16, out bf16.  MODE 2: A bf16, R bf16, out f32.
// ---------------------------------------------------------------------------
template <int MODE>
__global__ __launch_bounds__(256) void ln_k(
    const void* __restrict__ Ap, const void* __restrict__ Rp,
    const float* __restrict__ g, const float* __restrict__ bta,
    void* __restrict__ outp) {
  __shared__ float red[8];
  const int row = blockIdx.x, tid = threadIdx.x;
  const size_t base = (size_t)row * 1024 + tid * 4;
  float a4[4];
  {
    const bf16x4 a = *(const bf16x4*)((const unsigned short*)Ap + base);
    const bf16x4 rr = *(const bf16x4*)((const unsigned short*)Rp + base);
#pragma unroll
    for (int j = 0; j < 4; ++j)
      a4[j] = b2f((unsigned short)a[j]) + b2f((unsigned short)rr[j]);
  }
  float s = a4[0] + a4[1] + a4[2] + a4[3];
  float q = a4[0] * a4[0] + a4[1] * a4[1] + a4[2] * a4[2] + a4[3] * a4[3];
#pragma unroll
  for (int o = 32; o; o >>= 1) {
    s += __shfl_xor(s, o);
    q += __shfl_xor(q, o);
  }
  if ((tid & 63) == 0) {
    red[(tid >> 6) * 2] = s;
    red[(tid >> 6) * 2 + 1] = q;
  }
  __syncthreads();
  const float S = red[0] + red[2] + red[4] + red[6];
  const float Qs = red[1] + red[3] + red[5] + red[7];
  const float mean = S * (1.f / 1024.f);
  float var = (Qs - 1024.f * mean * mean) * (1.f / 1023.f);
  var = fmaxf(var, 0.f);
  const float inv = 1.f / (sqrtf(var) + 1e-6f);
  if (MODE == 2) {
    float4 o4;
    o4.x = g[tid * 4 + 0] * (a4[0] - mean) * inv + bta[tid * 4 + 0];
    o4.y = g[tid * 4 + 1] * (a4[1] - mean) * inv + bta[tid * 4 + 1];
    o4.z = g[tid * 4 + 2] * (a4[2] - mean) * inv + bta[tid * 4 + 2];
    o4.w = g[tid * 4 + 3] * (a4[3] - mean) * inv + bta[tid * 4 + 3];
    *(float4*)((float*)outp + base) = o4;
  } else {
    bf16x4 pb;
#pragma unroll
    for (int j = 0; j < 4; ++j) {
      const int col = tid * 4 + j;
      pb[j] = (short)f2b(g[col] * (a4[j] - mean) * inv + bta[col]);
    }
    *(bf16x4*)((unsigned short*)outp + base) = pb;
  }
}

// ---------------------------------------------------------------------------
// Fused (r13/r15-verified): input LN (+PE) for blocks < 4096; weight
// f32->bf16 convert + QKV bias pack for the rest. One dispatch.
// ---------------------------------------------------------------------------
__global__ __launch_bounds__(256) void prep_ln(
    const float* __restrict__ features, const float* __restrict__ g,
    const float* __restrict__ bta, unsigned short* __restrict__ xb,
    const float* __restrict__ Wq, const float* __restrict__ Wk,
    const float* __restrict__ Wv, const float* __restrict__ Wo,
    const float* __restrict__ W1, const float* __restrict__ W2,
    const float* __restrict__ bq, const float* __restrict__ bk,
    const float* __restrict__ bv, unsigned short* __restrict__ wqkv,
    unsigned short* __restrict__ wo, unsigned short* __restrict__ w1,
    unsigned short* __restrict__ w2, float* __restrict__ bqkv) {
  if (blockIdx.x < 4096) {
    __shared__ float red[8];
    const int row = blockIdx.x, tid = threadIdx.x;
    const size_t base = (size_t)row * 1024 + tid * 4;
    const float4 a = *(const float4*)(features + base);
    float a4[4] = {a.x, a.y, a.z, a.w};
    float s = a4[0] + a4[1] + a4[2] + a4[3];
    float q = a4[0] * a4[0] + a4[1] * a4[1] + a4[2] * a4[2] + a4[3] * a4[3];
#pragma unroll
    for (int o = 32; o; o >>= 1) {
      s += __shfl_xor(s, o);
      q += __shfl_xor(q, o);
    }
    if ((tid & 63) == 0) {
      red[(tid >> 6) * 2] = s;
      red[(tid >> 6) * 2 + 1] = q;
    }
    __syncthreads();
    const float S = red[0] + red[2] + red[4] + red[6];
    const float Qs = red[1] + red[3] + red[5] + red[7];
    const float mean = S * (1.f / 1024.f);
    float var = (Qs - 1024.f * mean * mean) * (1.f / 1023.f);
    var = fmaxf(var, 0.f);
    const float inv = 1.f / (sqrtf(var) + 1e-6f);
    bf16x4 pb;
#pragma unroll
    for (int j = 0; j < 4; ++j) {
      const int col = tid * 4 + j;
      float y = g[col] * (a4[j] - mean) * inv + bta[col];
      const float ang =
          (float)(row & 511) * exp2f((float)col * -0.025952563241307518f);
      y += (col & 1) ? cosf(ang) : sinf(ang);
      pb[j] = (short)f2b(y);
    }
    *(bf16x4*)(xb + base) = pb;
  } else {
    const int gid = (blockIdx.x - 4096) * 256 + threadIdx.x;
    if (gid < 1572864) {
      const int chunk = gid >> 18;
      const int off = (gid & 262143) * 4;
      const float* s;
      unsigned short* d;
      switch (chunk) {
        case 0: s = Wq; d = wqkv; break;
        case 1: s = Wk; d = wqkv + 1048576; break;
        case 2: s = Wv; d = wqkv + 2097152; break;
        case 3: s = Wo; d = wo; break;
        case 4: s = W1; d = w1; break;
        default: s = W2; d = w2; break;
      }
      const float4 v = *(const float4*)(s + off);
      bf16x4 o;
      o[0] = (short)f2b(v.x); o[1] = (short)f2b(v.y);
      o[2] = (short)f2b(v.z); o[3] = (short)f2b(v.w);
      *(bf16x4*)(d + off) = o;
    } else {
      const int idx = (gid - 1572864) * 4;
      if (idx < 3072) {
        const float* bs = idx < 1024 ? bq : (idx < 2048 ? bk - 1024 : bv - 2048);
        *(float4*)(bqkv + idx) = *(const float4*)(bs + idx);
      }
    }
  }
}

extern "C" void kernel_launch(void* const* d_in, const int* in_sizes, int n_in,
                              void* d_out, int out_size, void* d_ws, size_t ws_size,
                              hipStream_t stream) {
  (void)in_sizes; (void)n_in; (void)out_size; (void)ws_size;
  const float* features = (const float*)d_in[0];
  const int* mask = (const int*)d_in[1];
  const float* ln_in_g = (const float*)d_in[2];
  const float* ln_in_b = (const float*)d_in[3];
  const size_t DD = 1024 * 1024;
  // layer index 1 (the only live layer)
  const float* Wq = (const float*)d_in[4] + DD;
  const float* bq = (const float*)d_in[5] + 1024;
  const float* Wk = (const float*)d_in[6] + DD;
  const float* bk = (const float*)d_in[7] + 1024;
  const float* Wv = (const float*)d_in[8] + DD;
  const float* bv = (const float*)d_in[9] + 1024;
  const float* Wo = (const float*)d_in[10] + DD;
  const float* bo = (const float*)d_in[11] + 1024;
  const float* l1g = (const float*)d_in[12] + 1024;
  const float* l1b = (const float*)d_in[13] + 1024;
  const float* W1 = (const float*)d_in[14] + DD;
  const float* b1 = (const float*)d_in[15] + 1024;
  const float* W2 = (const float*)d_in[16] + DD;
  const float* b2 = (const float*)d_in[17] + 1024;
  const float* l2g = (const float*)d_in[18] + 1024;
  const float* l2b = (const float*)d_in[19] + 1024;

  char* base = (char*)d_ws;
  unsigned short* qkv = (unsigned short*)(base);              // 24 MB head-major
  unsigned short* xb = (unsigned short*)(base + 25165824);    // 8 MB: x bf16, then h
  unsigned short* ctxb = (unsigned short*)(base + 33554432);  // 8 MB: ctx, then s
  unsigned short* abuf = (unsigned short*)(base + 41943040);  // 8 MB: attn_out, then f
  unsigned short* wqkv = (unsigned short*)(base + 50331648);  // 6 MB [3072][1024]
  unsigned short* wo = (unsigned short*)(base + 56623104);    // 2 MB
  unsigned short* w1 = (unsigned short*)(base + 58720256);    // 2 MB
  unsigned short* w2 = (unsigned short*)(base + 60817408);    // 2 MB
  float* bqkv = (float*)(base + 62914560);                    // 12 KB

  hipFuncSetAttribute((const void*)gemm_t<128, 1>,
                      hipFuncAttributeMaxDynamicSharedMemorySize, 98304);
  hipFuncSetAttribute((const void*)gemm_t<64, 2>,
                      hipFuncAttributeMaxDynamicSharedMemorySize, 73728);
  hipFuncSetAttribute((const void*)gemm_t<64, 3>,
                      hipFuncAttributeMaxDynamicSharedMemorySize, 73728);
  hipFuncSetAttribute((const void*)attn_kernel,
                      hipFuncAttributeMaxDynamicSharedMemorySize, 67584);

  // fused: x = LN(features)+PE -> bf16  AND  weight converts + bias pack
  prep_ln<<<4096 + 6147, 256, 0, stream>>>(
      features, ln_in_g, ln_in_b, xb, Wq, Wk, Wv, Wo, W1, W2, bq, bk, bv,
      wqkv, wo, w1, w2, bqkv);
  // fused QKV projection -> head-major layout: 32m x 24n = 768 blocks
  gemm_t<128, 1><<<768, 256, 98304, stream>>>(xb, wqkv, bqkv, qkv, 3072, 1024, 12);
  // attention
  attn_kernel<<<1024, 256, 67584, stream>>>(qkv, mask, ctxb);
  // attn_out = ctx @ Wo^T + bo -> bf16 : 32m x 16n = 512 blocks
  gemm_t<64, 3><<<512, 256, 73728, stream>>>(ctxb, wo, bo, abuf, 1024, 1024, 8);
  // s = LN(attn_out + x) -> bf16 (overwrites ctx)
  ln_k<1><<<4096, 256, 0, stream>>>(abuf, xb, l1g, l1b, ctxb);
  // h = gelu(s @ W1^T + b1) -> bf16 (overwrites x)
  gemm_t<64, 2><<<512, 256, 73728, stream>>>(ctxb, w1, b1, xb, 1024, 1024, 8);
  // f = h @ W2^T + b2 -> bf16 (overwrites attn_out)
  gemm_t<64, 3><<<512, 256, 73728, stream>>>(xb, w2, b2, abuf, 1024, 1024, 8);
  // out = LN(f + s) -> f32
  ln_k<2><<<4096, 256, 0, stream>>>(abuf, ctxb, l2g, l2b, (float*)d_out);
}